// Round 1
// baseline (391.858 us; speedup 1.0000x reference)
//
#include <hip/hip_runtime.h>

typedef __attribute__((ext_vector_type(8))) short s16x8;
typedef __attribute__((ext_vector_type(4))) float f32x4;
typedef unsigned short u16;
typedef unsigned char u8;
typedef unsigned long long u64;

#define D_FEAT 128
#define TILE1 4096

__device__ __forceinline__ u16 f2bf(float f) {
    unsigned u = __builtin_bit_cast(unsigned, f);
    u = u + 0x7fffu + ((u >> 16) & 1u);   // RNE
    return (u16)(u >> 16);
}

// ---------------- x (fp32) -> bf16 ----------------
__global__ __launch_bounds__(256) void tobf16_kernel(const float4* __restrict__ X,
                                                     u16* __restrict__ out, int n4) {
    int i = blockIdx.x * 256 + threadIdx.x;
    if (i < n4) {
        float4 v = X[i];
        uint2 p;
        p.x = (unsigned)f2bf(v.x) | ((unsigned)f2bf(v.y) << 16);
        p.y = (unsigned)f2bf(v.z) | ((unsigned)f2bf(v.w) << 16);
        *(uint2*)(out + (size_t)i * 4) = p;
    }
}

// ---------------- CSR build via 2-pass bucket sort (LDS atomics only) ----------------
// pass 1a: per-(bucket, block) histogram.  bucket = dst >> 8  (bins = ceil(N/256) <= 256)
__global__ __launch_bounds__(256) void hist1_kernel(const int* __restrict__ dst,
                                                    int* __restrict__ ghist,
                                                    int E, int nb1, int bins) {
    __shared__ int h[256];
    const int t = threadIdx.x;
    h[t] = 0;
    __syncthreads();
    const int base = blockIdx.x * TILE1;
    #pragma unroll
    for (int j = 0; j < TILE1 / 256; ++j) {
        int e = base + j * 256 + t;
        if (e < E) atomicAdd(&h[dst[e] >> 8], 1);
    }
    __syncthreads();
    if (t < bins) ghist[t * nb1 + blockIdx.x] = h[t];
}

// pass 1b: one block.  bucket totals -> exclusive bucket bases; rewrite ghist in place
// to global exclusive offsets per (bucket, block).
__global__ __launch_bounds__(256) void scan1_kernel(int* __restrict__ ghist,
                                                    int* __restrict__ bbase,
                                                    int* __restrict__ row_start,
                                                    int nb1, int bins) {
    __shared__ int wt[4];
    const int t = threadIdx.x, lane = t & 63, wid = t >> 6;
    int total = 0;
    if (t < bins)
        for (int b = 0; b < nb1; ++b) total += ghist[t * nb1 + b];
    int s = total;
    #pragma unroll
    for (int off = 1; off < 64; off <<= 1) {
        int u = __shfl_up(s, off, 64);
        if (lane >= off) s += u;
    }
    if (lane == 63) wt[wid] = s;
    __syncthreads();
    int add = 0;
    #pragma unroll
    for (int w = 0; w < 4; ++w) add += (w < wid) ? wt[w] : 0;
    const int excl = s + add - total;          // exclusive scan of bucket totals
    if (t <= bins) bbase[t] = excl;            // bbase[bins] == E sentinel
    if (t == 0) row_start[0] = 0;
    if (t < bins) {
        int run = excl;
        for (int b = 0; b < nb1; ++b) {
            int v = ghist[t * nb1 + b];
            ghist[t * nb1 + b] = run;
            run += v;
        }
    }
}

// pass 1c: scatter edges into bucket-partitioned u64 buffer.
// rec = (dst << 32) | src | (code << 16).  Positions per block are contiguous runs
// inside each bucket -> write amplification ~3 lines/bucket/block instead of 1 line/edge.
__global__ __launch_bounds__(256) void scatter1_kernel(const int* __restrict__ src,
                                                       const int* __restrict__ dst,
                                                       const int* __restrict__ eattr,
                                                       const int* __restrict__ ghist,
                                                       u64* __restrict__ buf1,
                                                       int E, int nb1, int bins) {
    __shared__ int lofs[256];
    const int t = threadIdx.x;
    if (t < bins) lofs[t] = ghist[t * nb1 + blockIdx.x];
    __syncthreads();
    const int base = blockIdx.x * TILE1;
    #pragma unroll
    for (int j = 0; j < TILE1 / 256; ++j) {
        int e = base + j * 256 + t;
        if (e < E) {
            int d = dst[e];
            int2 at = ((const int2*)eattr)[e];
            unsigned pay = (unsigned)src[e] | ((unsigned)(at.x * 3 + at.y) << 16);
            int pos = atomicAdd(&lofs[d >> 8], 1);
            buf1[pos] = ((u64)(unsigned)d << 32) | pay;
        }
    }
}

// pass 2: one block per bucket.  Counting sort by local node (dst & 255) inside the
// bucket (all data L2-hot); emits final edges[] run + row_start[] from the block scan.
__global__ __launch_bounds__(256) void bucket2_kernel(const u64* __restrict__ buf1,
                                                      const int* __restrict__ bbase,
                                                      int* __restrict__ row_start,
                                                      unsigned* __restrict__ edges, int N) {
    __shared__ int cnt[256];
    __shared__ int cur[256];
    __shared__ int wt[4];
    const int t = threadIdx.x, lane = t & 63, wid = t >> 6;
    const int bin = blockIdx.x;
    const int lo = bbase[bin], hi = bbase[bin + 1];
    cnt[t] = 0;
    __syncthreads();
    for (int i = lo + t; i < hi; i += 256)
        atomicAdd(&cnt[(int)(buf1[i] >> 32) & 255], 1);
    __syncthreads();
    const int v = cnt[t];
    int s = v;
    #pragma unroll
    for (int off = 1; off < 64; off <<= 1) {
        int u = __shfl_up(s, off, 64);
        if (lane >= off) s += u;
    }
    if (lane == 63) wt[wid] = s;
    __syncthreads();
    int add = 0;
    #pragma unroll
    for (int w = 0; w < 4; ++w) add += (w < wid) ? wt[w] : 0;
    const int incl = s + add;
    const int g = bin * 256 + t;
    if (g < N) row_start[g + 1] = lo + incl;
    cur[t] = incl - v;
    __syncthreads();
    for (int i = lo + t; i < hi; i += 256) {
        u64 rec = buf1[i];
        int loc = atomicAdd(&cur[(int)(rec >> 32) & 255], 1);
        edges[lo + loc] = (unsigned)rec;
    }
}

// ---------------- weight prep: fp32 in -> transposed bf16 out ----------------
__global__ __launch_bounds__(256) void transpose_kernel(const float* __restrict__ W1_0,
                                                        const float* __restrict__ W2_0,
                                                        const float* __restrict__ W1_1,
                                                        const float* __restrict__ W2_1,
                                                        u16* __restrict__ out) {
    int mat = blockIdx.y;
    const float* s = (mat == 0) ? W1_0 : (mat == 1) ? W2_0 : (mat == 2) ? W1_1 : W2_1;
    int K = (mat & 1) ? 256 : 128;
    int Nc = 384 - K;
    u16* d = out + mat * 32768;
    int idx = blockIdx.x * 256 + threadIdx.x;
    int n = idx / K, k = idx - n * K;
    d[idx] = f2bf(s[k * Nc + n]);
}

__global__ __launch_bounds__(128) void emb_kernel(const float* __restrict__ ee1_0,
                                                  const float* __restrict__ ee2_0,
                                                  const float* __restrict__ ee1_1,
                                                  const float* __restrict__ ee2_1,
                                                  float* __restrict__ emb) {
    int code = blockIdx.x;
    int layer = blockIdx.y;
    int d = threadIdx.x;
    int a0 = code / 3, a1 = code - a0 * 3;
    const float* e1 = layer ? ee1_1 : ee1_0;
    const float* e2 = layer ? ee2_1 : ee2_0;
    emb[layer * 18 * 128 + code * 128 + d] = e1[a0 * 128 + d] + e2[a1 * 128 + d];
}

// ---------------- aggregation: one wave per node, 8-way batched bf16 gather ----------------
__global__ __launch_bounds__(256) void aggregate_kernel(const u16* __restrict__ X,
                                                        const int* __restrict__ row_start,
                                                        const unsigned* __restrict__ edges,
                                                        const float* __restrict__ emb,
                                                        u16* __restrict__ A, int N) {
    __shared__ float semb[18 * 128];
    for (int i = threadIdx.x; i < 18 * 128; i += 256) semb[i] = emb[i];
    __syncthreads();
    const int node = blockIdx.x * 4 + (threadIdx.x >> 6);
    const int lane = threadIdx.x & 63;
    if (node >= N) return;
    const int s = row_start[node], e = row_start[node + 1];
    const float2* sem2 = (const float2*)semb;
    const u16* xl = X + lane * 2;
    float a0 = 0.f, a1 = 0.f;
    int i = s;
    for (; i + 8 <= e; i += 8) {
        unsigned xv[8];
        float2 ev[8];
        unsigned p[8];
        #pragma unroll
        for (int j = 0; j < 8; ++j) p[j] = edges[i + j];
        #pragma unroll
        for (int j = 0; j < 8; ++j)
            xv[j] = *(const unsigned*)(xl + (p[j] & 0xFFFFu) * D_FEAT);
        #pragma unroll
        for (int j = 0; j < 8; ++j) ev[j] = sem2[(int)(p[j] >> 16) * 64 + lane];
        #pragma unroll
        for (int j = 0; j < 8; ++j) {
            a0 += __builtin_bit_cast(float, xv[j] << 16) + ev[j].x;
            a1 += __builtin_bit_cast(float, xv[j] & 0xFFFF0000u) + ev[j].y;
        }
    }
    for (; i < e; ++i) {
        unsigned p = edges[i];
        unsigned xv = *(const unsigned*)(xl + (p & 0xFFFFu) * D_FEAT);
        float2 ev = sem2[(int)(p >> 16) * 64 + lane];
        a0 += __builtin_bit_cast(float, xv << 16) + ev.x;
        a1 += __builtin_bit_cast(float, xv & 0xFFFF0000u) + ev.y;
    }
    unsigned out = (unsigned)f2bf(a0) | ((unsigned)f2bf(a1) << 16);
    *(unsigned*)(A + node * D_FEAT + lane * 2) = out;
}

// ---------------- fused MLP with LDS-staged weights (round-8 verbatim) ----------------
#define HPAD 264
template <bool RELU2, bool OUTF32>
__global__ __launch_bounds__(256, 1) void mlp_kernel(const u16* __restrict__ A,
                                                     const u16* __restrict__ B1t,
                                                     const float* __restrict__ bias1,
                                                     const u16* __restrict__ B2t,
                                                     const float* __restrict__ bias2,
                                                     void* __restrict__ C, int M) {
    __shared__ __align__(16) u16 wbuf[32768];
    __shared__ __align__(16) u16 hh[4][16][HPAD];
    const int tid = threadIdx.x;
    const int wave = tid >> 6;
    const int lane = tid & 63;
    const int m16 = lane & 15;
    const int quad = lane >> 4;

    const int row0 = blockIdx.x * 64 + wave * 16;
    const int arow = row0 + m16;
    const bool avalid = arow < M;

    // stage W1t (src-linear reads, frag-ordered LDS writes)
    {
        const uint4* src = (const uint4*)B1t;
        #pragma unroll
        for (int i = 0; i < 16; ++i) {
            int s = i * 256 + tid;
            uint4 v = src[s];
            int c = (((s >> 8) * 4 + ((s >> 2) & 3)) << 6) | ((s & 3) << 4) | ((s >> 4) & 15);
            *(uint4*)(wbuf + c * 8) = v;
        }
    }

    s16x8 af[4];
    #pragma unroll
    for (int kb = 0; kb < 4; ++kb) af[kb] = s16x8{};
    if (avalid) {
        #pragma unroll
        for (int kb = 0; kb < 4; ++kb)
            af[kb] = *(const s16x8*)(A + arow * 128 + kb * 32 + quad * 8);
    }
    float b1v[16];
    #pragma unroll
    for (int t = 0; t < 16; ++t) b1v[t] = bias1[t * 16 + m16];

    __syncthreads();

    f32x4 acc[16];
    #pragma unroll
    for (int t = 0; t < 16; ++t) acc[t] = f32x4{0, 0, 0, 0};

    #pragma unroll
    for (int kb = 0; kb < 4; ++kb) {
        #pragma unroll
        for (int t = 0; t < 16; ++t) {
            s16x8 bf = *(const s16x8*)(wbuf + (((((t << 2) | kb) << 6) | lane) * 8));
            acc[t] = __builtin_amdgcn_mfma_f32_16x16x32_bf16(af[kb], bf, acc[t], 0, 0, 0);
        }
    }

    #pragma unroll
    for (int t = 0; t < 16; ++t) {
        const int col = t * 16 + m16;
        #pragma unroll
        for (int r = 0; r < 4; ++r) {
            float v = acc[t][r] + b1v[t];
            v = v > 0.f ? v : 0.f;
            hh[wave][quad * 4 + r][col] = f2bf(v);
        }
    }
    __syncthreads();

    // stage W2t
    {
        const uint4* src = (const uint4*)B2t;
        #pragma unroll
        for (int i = 0; i < 16; ++i) {
            int s = i * 256 + tid;
            uint4 v = src[s];
            int c = (((s >> 9) * 8 + ((s >> 2) & 7)) << 6) | ((s & 3) << 4) | ((s >> 5) & 15);
            *(uint4*)(wbuf + c * 8) = v;
        }
    }
    float b2v[8];
    #pragma unroll
    for (int t = 0; t < 8; ++t) b2v[t] = bias2[t * 16 + m16];

    __syncthreads();

    f32x4 acc2[8];
    #pragma unroll
    for (int t = 0; t < 8; ++t) acc2[t] = f32x4{0, 0, 0, 0};

    #pragma unroll
    for (int kb = 0; kb < 8; ++kb) {
        s16x8 haf = *(const s16x8*)(&hh[wave][m16][kb * 32 + quad * 8]);
        #pragma unroll
        for (int t = 0; t < 8; ++t) {
            s16x8 bf = *(const s16x8*)(wbuf + (((((t << 3) | kb) << 6) | lane) * 8));
            acc2[t] = __builtin_amdgcn_mfma_f32_16x16x32_bf16(haf, bf, acc2[t], 0, 0, 0);
        }
    }

    #pragma unroll
    for (int t = 0; t < 8; ++t) {
        const int col = t * 16 + m16;
        #pragma unroll
        for (int r = 0; r < 4; ++r) {
            const int row = row0 + quad * 4 + r;
            if (row < M) {
                float v = acc2[t][r] + b2v[t];
                if (RELU2) v = v > 0.f ? v : 0.f;
                if (OUTF32) ((float*)C)[row * 128 + col] = v;
                else        ((u16*)C)[row * 128 + col] = f2bf(v);
            }
        }
    }
}

extern "C" void kernel_launch(void* const* d_in, const int* in_sizes, int n_in,
                              void* d_out, int out_size, void* d_ws, size_t ws_size,
                              hipStream_t stream) {
    const int N = in_sizes[0] / D_FEAT;     // 50000
    const int E = in_sizes[1] / 2;          // 800000

    const float* x    = (const float*)d_in[0];
    const int* eidx   = (const int*)d_in[1];
    const int* eattr  = (const int*)d_in[2];
    const float* ee1_0 = (const float*)d_in[3];
    const float* ee2_0 = (const float*)d_in[4];
    const float* W1_0  = (const float*)d_in[5];
    const float* b1_0  = (const float*)d_in[6];
    const float* W2_0  = (const float*)d_in[7];
    const float* b2_0  = (const float*)d_in[8];
    const float* ee1_1 = (const float*)d_in[9];
    const float* ee2_1 = (const float*)d_in[10];
    const float* W1_1  = (const float*)d_in[11];
    const float* b1_1  = (const float*)d_in[12];
    const float* W2_1  = (const float*)d_in[13];
    const float* b2_1  = (const float*)d_in[14];

    const int nb1  = (E + TILE1 - 1) / TILE1;     // 196 pass-1 blocks
    const int bins = (N + 255) / 256;             // 196 buckets

    // workspace
    char* ws = (char*)d_ws;
    size_t off = 0;
    auto alloc = [&](size_t bytes) { size_t o = off; off = (off + bytes + 255) & ~(size_t)255; return o; };
    size_t o_rowstart = alloc((size_t)(N + 1) * 4);
    size_t o_edges    = alloc((size_t)E * 4);
    size_t o_ghist    = alloc((size_t)bins * nb1 * 4);
    size_t o_base     = alloc((size_t)(bins + 1) * 4);
    size_t o_emb      = alloc(2 * 18 * 128 * 4);
    size_t o_wt       = alloc(4 * 32768 * 2);
    size_t o_aa       = alloc((size_t)N * D_FEAT * 2);

    int*      row_start = (int*)(ws + o_rowstart);
    unsigned* edges     = (unsigned*)(ws + o_edges);
    int*      ghist     = (int*)(ws + o_ghist);
    int*      bbase     = (int*)(ws + o_base);
    float*    emb       = (float*)(ws + o_emb);
    u16*      W1t_0     = (u16*)(ws + o_wt);
    u16*      W2t_0     = W1t_0 + 32768;
    u16*      W1t_1     = W2t_0 + 32768;
    u16*      W2t_1     = W1t_1 + 32768;
    u16*      AA        = (u16*)(ws + o_aa);
    u64*      buf1      = (u64*)(ws + o_aa);      // aliases AA: E*8 = 6.4MB <= N*128*2, dead before aggregate

    // d_out (fp32, 25.6 MB) staging: front = X2 (bf16 L0 output), back = xb (bf16 x)
    u16* X2 = (u16*)d_out;
    u16* xb = (u16*)d_out + (size_t)N * D_FEAT;

    const int rows64 = (N + 63) / 64;             // 782
    const int aggB = (N + 3) / 4;
    const int n4 = N * D_FEAT / 4;

    tobf16_kernel<<<(n4 + 255) / 256, 256, 0, stream>>>((const float4*)x, xb, n4);

    // CSR build: 2-pass bucket sort, no global atomics
    hist1_kernel<<<nb1, 256, 0, stream>>>(eidx + E, ghist, E, nb1, bins);
    scan1_kernel<<<1, 256, 0, stream>>>(ghist, bbase, row_start, nb1, bins);
    scatter1_kernel<<<nb1, 256, 0, stream>>>(eidx, eidx + E, eattr, ghist, buf1, E, nb1, bins);
    bucket2_kernel<<<bins, 256, 0, stream>>>(buf1, bbase, row_start, edges, N);

    // prep
    emb_kernel<<<dim3(18, 2), 128, 0, stream>>>(ee1_0, ee2_0, ee1_1, ee2_1, emb);
    transpose_kernel<<<dim3(128, 4), 256, 0, stream>>>(W1_0, W2_0, W1_1, W2_1, W1t_0);

    // layer 0: xb -> AA -> X2
    aggregate_kernel<<<aggB, 256, 0, stream>>>(xb, row_start, edges, emb, AA, N);
    mlp_kernel<true, false><<<rows64, 256, 0, stream>>>(AA, W1t_0, b1_0, W2t_0, b2_0, X2, N);

    // layer 1: X2 -> AA -> d_out (fp32)
    aggregate_kernel<<<aggB, 256, 0, stream>>>(X2, row_start, edges, emb + 18 * 128, AA, N);
    mlp_kernel<false, true><<<rows64, 256, 0, stream>>>(AA, W1t_1, b1_1, W2t_1, b2_1, d_out, N);
}

// Round 2
// 325.450 us; speedup vs baseline: 1.2040x; 1.2040x over previous
//
#include <hip/hip_runtime.h>

typedef __attribute__((ext_vector_type(8))) short s16x8;
typedef __attribute__((ext_vector_type(4))) float f32x4;
typedef unsigned short u16;
typedef unsigned char u8;
typedef unsigned long long u64;

#define D_FEAT 128
#define TILE1 4096

__device__ __forceinline__ u16 f2bf(float f) {
    unsigned u = __builtin_bit_cast(unsigned, f);
    u = u + 0x7fffu + ((u >> 16) & 1u);   // RNE
    return (u16)(u >> 16);
}

// ---------------- x (fp32) -> bf16 ----------------
__global__ __launch_bounds__(256) void tobf16_kernel(const float4* __restrict__ X,
                                                     u16* __restrict__ out, int n4) {
    int i = blockIdx.x * 256 + threadIdx.x;
    if (i < n4) {
        float4 v = X[i];
        uint2 p;
        p.x = (unsigned)f2bf(v.x) | ((unsigned)f2bf(v.y) << 16);
        p.y = (unsigned)f2bf(v.z) | ((unsigned)f2bf(v.w) << 16);
        *(uint2*)(out + (size_t)i * 4) = p;
    }
}

// ---------------- CSR build via 2-pass bucket sort (LDS atomics only) ----------------
// pass 1a: per-(bucket, block) histogram.  bucket = dst >> 8  (bins = ceil(N/256) <= 256)
__global__ __launch_bounds__(256) void hist1_kernel(const int* __restrict__ dst,
                                                    int* __restrict__ ghist,
                                                    int E, int nb1, int bins) {
    __shared__ int h[256];
    const int t = threadIdx.x;
    h[t] = 0;
    __syncthreads();
    const int base = blockIdx.x * TILE1;
    #pragma unroll
    for (int j = 0; j < TILE1 / 256; ++j) {
        int e = base + j * 256 + t;
        if (e < E) atomicAdd(&h[dst[e] >> 8], 1);
    }
    __syncthreads();
    if (t < bins) ghist[t * nb1 + blockIdx.x] = h[t];
}

// pass 1b-a: one block PER BUCKET.  Wave-scan the bucket's row of nb1 per-block
// counts -> exclusive offsets relative to bucket start (in place) + bucket total.
__global__ __launch_bounds__(256) void scan1a_kernel(int* __restrict__ ghist,
                                                     int* __restrict__ btot, int nb1) {
    __shared__ int wt[4];
    const int t = threadIdx.x, lane = t & 63, wid = t >> 6;
    const int bin = blockIdx.x;
    const int v = (t < nb1) ? ghist[bin * nb1 + t] : 0;
    int s = v;
    #pragma unroll
    for (int off = 1; off < 64; off <<= 1) {
        int u = __shfl_up(s, off, 64);
        if (lane >= off) s += u;
    }
    if (lane == 63) wt[wid] = s;
    __syncthreads();
    int add = 0;
    #pragma unroll
    for (int w = 0; w < 4; ++w) add += (w < wid) ? wt[w] : 0;
    s += add;                                   // inclusive
    if (t < nb1) ghist[bin * nb1 + t] = s - v;  // exclusive, bucket-relative
    if (t == 255) btot[bin] = s;                // bucket total
}

// pass 1b-b: one tiny block.  Scan bucket totals -> exclusive bucket bases.
__global__ __launch_bounds__(256) void scan1b_kernel(const int* __restrict__ btot,
                                                     int* __restrict__ bbase,
                                                     int* __restrict__ row_start, int bins) {
    __shared__ int wt[4];
    const int t = threadIdx.x, lane = t & 63, wid = t >> 6;
    const int v = (t < bins) ? btot[t] : 0;
    int s = v;
    #pragma unroll
    for (int off = 1; off < 64; off <<= 1) {
        int u = __shfl_up(s, off, 64);
        if (lane >= off) s += u;
    }
    if (lane == 63) wt[wid] = s;
    __syncthreads();
    int add = 0;
    #pragma unroll
    for (int w = 0; w < 4; ++w) add += (w < wid) ? wt[w] : 0;
    s += add;                                   // inclusive
    if (t < bins) bbase[t] = s - v;             // exclusive
    if (t == 255) bbase[bins] = s;              // == E sentinel (zeros padded)
    if (t == 0) row_start[0] = 0;
}

// pass 1c: scatter edges into bucket-partitioned u64 buffer.
// rec = (dst << 32) | src | (code << 16).  Positions per block are contiguous runs
// inside each bucket -> write amplification ~3 lines/bucket/block instead of 1 line/edge.
__global__ __launch_bounds__(256) void scatter1_kernel(const int* __restrict__ src,
                                                       const int* __restrict__ dst,
                                                       const int* __restrict__ eattr,
                                                       const int* __restrict__ ghist,
                                                       const int* __restrict__ bbase,
                                                       u64* __restrict__ buf1,
                                                       int E, int nb1, int bins) {
    __shared__ int lofs[256];
    const int t = threadIdx.x;
    if (t < bins) lofs[t] = bbase[t] + ghist[t * nb1 + blockIdx.x];
    __syncthreads();
    const int base = blockIdx.x * TILE1;
    #pragma unroll
    for (int j = 0; j < TILE1 / 256; ++j) {
        int e = base + j * 256 + t;
        if (e < E) {
            int d = dst[e];
            int2 at = ((const int2*)eattr)[e];
            unsigned pay = (unsigned)src[e] | ((unsigned)(at.x * 3 + at.y) << 16);
            int pos = atomicAdd(&lofs[d >> 8], 1);
            buf1[pos] = ((u64)(unsigned)d << 32) | pay;
        }
    }
}

// pass 2: one block per bucket.  Counting sort by local node (dst & 255) inside the
// bucket (all data L2-hot); emits final edges[] run + row_start[] from the block scan.
__global__ __launch_bounds__(256) void bucket2_kernel(const u64* __restrict__ buf1,
                                                      const int* __restrict__ bbase,
                                                      int* __restrict__ row_start,
                                                      unsigned* __restrict__ edges, int N) {
    __shared__ int cnt[256];
    __shared__ int cur[256];
    __shared__ int wt[4];
    const int t = threadIdx.x, lane = t & 63, wid = t >> 6;
    const int bin = blockIdx.x;
    const int lo = bbase[bin], hi = bbase[bin + 1];
    cnt[t] = 0;
    __syncthreads();
    for (int i = lo + t; i < hi; i += 256)
        atomicAdd(&cnt[(int)(buf1[i] >> 32) & 255], 1);
    __syncthreads();
    const int v = cnt[t];
    int s = v;
    #pragma unroll
    for (int off = 1; off < 64; off <<= 1) {
        int u = __shfl_up(s, off, 64);
        if (lane >= off) s += u;
    }
    if (lane == 63) wt[wid] = s;
    __syncthreads();
    int add = 0;
    #pragma unroll
    for (int w = 0; w < 4; ++w) add += (w < wid) ? wt[w] : 0;
    const int incl = s + add;
    const int g = bin * 256 + t;
    if (g < N) row_start[g + 1] = lo + incl;
    cur[t] = incl - v;
    __syncthreads();
    for (int i = lo + t; i < hi; i += 256) {
        u64 rec = buf1[i];
        int loc = atomicAdd(&cur[(int)(rec >> 32) & 255], 1);
        edges[lo + loc] = (unsigned)rec;
    }
}

// ---------------- weight prep: fp32 in -> transposed bf16 out ----------------
__global__ __launch_bounds__(256) void transpose_kernel(const float* __restrict__ W1_0,
                                                        const float* __restrict__ W2_0,
                                                        const float* __restrict__ W1_1,
                                                        const float* __restrict__ W2_1,
                                                        u16* __restrict__ out) {
    int mat = blockIdx.y;
    const float* s = (mat == 0) ? W1_0 : (mat == 1) ? W2_0 : (mat == 2) ? W1_1 : W2_1;
    int K = (mat & 1) ? 256 : 128;
    int Nc = 384 - K;
    u16* d = out + mat * 32768;
    int idx = blockIdx.x * 256 + threadIdx.x;
    int n = idx / K, k = idx - n * K;
    d[idx] = f2bf(s[k * Nc + n]);
}

__global__ __launch_bounds__(128) void emb_kernel(const float* __restrict__ ee1_0,
                                                  const float* __restrict__ ee2_0,
                                                  const float* __restrict__ ee1_1,
                                                  const float* __restrict__ ee2_1,
                                                  float* __restrict__ emb) {
    int code = blockIdx.x;
    int layer = blockIdx.y;
    int d = threadIdx.x;
    int a0 = code / 3, a1 = code - a0 * 3;
    const float* e1 = layer ? ee1_1 : ee1_0;
    const float* e2 = layer ? ee2_1 : ee2_0;
    emb[layer * 18 * 128 + code * 128 + d] = e1[a0 * 128 + d] + e2[a1 * 128 + d];
}

// ---------------- aggregation: one wave per node, 8-way batched bf16 gather ----------------
__global__ __launch_bounds__(256) void aggregate_kernel(const u16* __restrict__ X,
                                                        const int* __restrict__ row_start,
                                                        const unsigned* __restrict__ edges,
                                                        const float* __restrict__ emb,
                                                        u16* __restrict__ A, int N) {
    __shared__ float semb[18 * 128];
    for (int i = threadIdx.x; i < 18 * 128; i += 256) semb[i] = emb[i];
    __syncthreads();
    const int node = blockIdx.x * 4 + (threadIdx.x >> 6);
    const int lane = threadIdx.x & 63;
    if (node >= N) return;
    const int s = row_start[node], e = row_start[node + 1];
    const float2* sem2 = (const float2*)semb;
    const u16* xl = X + lane * 2;
    float a0 = 0.f, a1 = 0.f;
    int i = s;
    for (; i + 8 <= e; i += 8) {
        unsigned xv[8];
        float2 ev[8];
        unsigned p[8];
        #pragma unroll
        for (int j = 0; j < 8; ++j) p[j] = edges[i + j];
        #pragma unroll
        for (int j = 0; j < 8; ++j)
            xv[j] = *(const unsigned*)(xl + (p[j] & 0xFFFFu) * D_FEAT);
        #pragma unroll
        for (int j = 0; j < 8; ++j) ev[j] = sem2[(int)(p[j] >> 16) * 64 + lane];
        #pragma unroll
        for (int j = 0; j < 8; ++j) {
            a0 += __builtin_bit_cast(float, xv[j] << 16) + ev[j].x;
            a1 += __builtin_bit_cast(float, xv[j] & 0xFFFF0000u) + ev[j].y;
        }
    }
    for (; i < e; ++i) {
        unsigned p = edges[i];
        unsigned xv = *(const unsigned*)(xl + (p & 0xFFFFu) * D_FEAT);
        float2 ev = sem2[(int)(p >> 16) * 64 + lane];
        a0 += __builtin_bit_cast(float, xv << 16) + ev.x;
        a1 += __builtin_bit_cast(float, xv & 0xFFFF0000u) + ev.y;
    }
    unsigned out = (unsigned)f2bf(a0) | ((unsigned)f2bf(a1) << 16);
    *(unsigned*)(A + node * D_FEAT + lane * 2) = out;
}

// ---------------- fused MLP with LDS-staged weights (round-8 verbatim) ----------------
#define HPAD 264
template <bool RELU2, bool OUTF32>
__global__ __launch_bounds__(256, 1) void mlp_kernel(const u16* __restrict__ A,
                                                     const u16* __restrict__ B1t,
                                                     const float* __restrict__ bias1,
                                                     const u16* __restrict__ B2t,
                                                     const float* __restrict__ bias2,
                                                     void* __restrict__ C, int M) {
    __shared__ __align__(16) u16 wbuf[32768];
    __shared__ __align__(16) u16 hh[4][16][HPAD];
    const int tid = threadIdx.x;
    const int wave = tid >> 6;
    const int lane = tid & 63;
    const int m16 = lane & 15;
    const int quad = lane >> 4;

    const int row0 = blockIdx.x * 64 + wave * 16;
    const int arow = row0 + m16;
    const bool avalid = arow < M;

    // stage W1t (src-linear reads, frag-ordered LDS writes)
    {
        const uint4* src = (const uint4*)B1t;
        #pragma unroll
        for (int i = 0; i < 16; ++i) {
            int s = i * 256 + tid;
            uint4 v = src[s];
            int c = (((s >> 8) * 4 + ((s >> 2) & 3)) << 6) | ((s & 3) << 4) | ((s >> 4) & 15);
            *(uint4*)(wbuf + c * 8) = v;
        }
    }

    s16x8 af[4];
    #pragma unroll
    for (int kb = 0; kb < 4; ++kb) af[kb] = s16x8{};
    if (avalid) {
        #pragma unroll
        for (int kb = 0; kb < 4; ++kb)
            af[kb] = *(const s16x8*)(A + arow * 128 + kb * 32 + quad * 8);
    }
    float b1v[16];
    #pragma unroll
    for (int t = 0; t < 16; ++t) b1v[t] = bias1[t * 16 + m16];

    __syncthreads();

    f32x4 acc[16];
    #pragma unroll
    for (int t = 0; t < 16; ++t) acc[t] = f32x4{0, 0, 0, 0};

    #pragma unroll
    for (int kb = 0; kb < 4; ++kb) {
        #pragma unroll
        for (int t = 0; t < 16; ++t) {
            s16x8 bf = *(const s16x8*)(wbuf + (((((t << 2) | kb) << 6) | lane) * 8));
            acc[t] = __builtin_amdgcn_mfma_f32_16x16x32_bf16(af[kb], bf, acc[t], 0, 0, 0);
        }
    }

    #pragma unroll
    for (int t = 0; t < 16; ++t) {
        const int col = t * 16 + m16;
        #pragma unroll
        for (int r = 0; r < 4; ++r) {
            float v = acc[t][r] + b1v[t];
            v = v > 0.f ? v : 0.f;
            hh[wave][quad * 4 + r][col] = f2bf(v);
        }
    }
    __syncthreads();

    // stage W2t
    {
        const uint4* src = (const uint4*)B2t;
        #pragma unroll
        for (int i = 0; i < 16; ++i) {
            int s = i * 256 + tid;
            uint4 v = src[s];
            int c = (((s >> 9) * 8 + ((s >> 2) & 7)) << 6) | ((s & 3) << 4) | ((s >> 5) & 15);
            *(uint4*)(wbuf + c * 8) = v;
        }
    }
    float b2v[8];
    #pragma unroll
    for (int t = 0; t < 8; ++t) b2v[t] = bias2[t * 16 + m16];

    __syncthreads();

    f32x4 acc2[8];
    #pragma unroll
    for (int t = 0; t < 8; ++t) acc2[t] = f32x4{0, 0, 0, 0};

    #pragma unroll
    for (int kb = 0; kb < 8; ++kb) {
        s16x8 haf = *(const s16x8*)(&hh[wave][m16][kb * 32 + quad * 8]);
        #pragma unroll
        for (int t = 0; t < 8; ++t) {
            s16x8 bf = *(const s16x8*)(wbuf + (((((t << 3) | kb) << 6) | lane) * 8));
            acc2[t] = __builtin_amdgcn_mfma_f32_16x16x32_bf16(haf, bf, acc2[t], 0, 0, 0);
        }
    }

    #pragma unroll
    for (int t = 0; t < 8; ++t) {
        const int col = t * 16 + m16;
        #pragma unroll
        for (int r = 0; r < 4; ++r) {
            const int row = row0 + quad * 4 + r;
            if (row < M) {
                float v = acc2[t][r] + b2v[t];
                if (RELU2) v = v > 0.f ? v : 0.f;
                if (OUTF32) ((float*)C)[row * 128 + col] = v;
                else        ((u16*)C)[row * 128 + col] = f2bf(v);
            }
        }
    }
}

extern "C" void kernel_launch(void* const* d_in, const int* in_sizes, int n_in,
                              void* d_out, int out_size, void* d_ws, size_t ws_size,
                              hipStream_t stream) {
    const int N = in_sizes[0] / D_FEAT;     // 50000
    const int E = in_sizes[1] / 2;          // 800000

    const float* x    = (const float*)d_in[0];
    const int* eidx   = (const int*)d_in[1];
    const int* eattr  = (const int*)d_in[2];
    const float* ee1_0 = (const float*)d_in[3];
    const float* ee2_0 = (const float*)d_in[4];
    const float* W1_0  = (const float*)d_in[5];
    const float* b1_0  = (const float*)d_in[6];
    const float* W2_0  = (const float*)d_in[7];
    const float* b2_0  = (const float*)d_in[8];
    const float* ee1_1 = (const float*)d_in[9];
    const float* ee2_1 = (const float*)d_in[10];
    const float* W1_1  = (const float*)d_in[11];
    const float* b1_1  = (const float*)d_in[12];
    const float* W2_1  = (const float*)d_in[13];
    const float* b2_1  = (const float*)d_in[14];

    const int nb1  = (E + TILE1 - 1) / TILE1;     // 196 pass-1 blocks
    const int bins = (N + 255) / 256;             // 196 buckets

    // workspace
    char* ws = (char*)d_ws;
    size_t off = 0;
    auto alloc = [&](size_t bytes) { size_t o = off; off = (off + bytes + 255) & ~(size_t)255; return o; };
    size_t o_rowstart = alloc((size_t)(N + 1) * 4);
    size_t o_edges    = alloc((size_t)E * 4);
    size_t o_ghist    = alloc((size_t)bins * nb1 * 4);
    size_t o_base     = alloc((size_t)(bins + 1) * 4);
    size_t o_btot     = alloc((size_t)bins * 4);
    size_t o_emb      = alloc(2 * 18 * 128 * 4);
    size_t o_wt       = alloc(4 * 32768 * 2);
    size_t o_aa       = alloc((size_t)N * D_FEAT * 2);

    int*      row_start = (int*)(ws + o_rowstart);
    unsigned* edges     = (unsigned*)(ws + o_edges);
    int*      ghist     = (int*)(ws + o_ghist);
    int*      bbase     = (int*)(ws + o_base);
    int*      btot      = (int*)(ws + o_btot);
    float*    emb       = (float*)(ws + o_emb);
    u16*      W1t_0     = (u16*)(ws + o_wt);
    u16*      W2t_0     = W1t_0 + 32768;
    u16*      W1t_1     = W2t_0 + 32768;
    u16*      W2t_1     = W1t_1 + 32768;
    u16*      AA        = (u16*)(ws + o_aa);
    u64*      buf1      = (u64*)(ws + o_aa);      // aliases AA: E*8 = 6.4MB <= N*128*2, dead before aggregate

    // d_out (fp32, 25.6 MB) staging: front = X2 (bf16 L0 output), back = xb (bf16 x)
    u16* X2 = (u16*)d_out;
    u16* xb = (u16*)d_out + (size_t)N * D_FEAT;

    const int rows64 = (N + 63) / 64;             // 782
    const int aggB = (N + 3) / 4;
    const int n4 = N * D_FEAT / 4;

    tobf16_kernel<<<(n4 + 255) / 256, 256, 0, stream>>>((const float4*)x, xb, n4);

    // CSR build: 2-pass bucket sort, hierarchical scan, no global atomics
    hist1_kernel<<<nb1, 256, 0, stream>>>(eidx + E, ghist, E, nb1, bins);
    scan1a_kernel<<<bins, 256, 0, stream>>>(ghist, btot, nb1);
    scan1b_kernel<<<1, 256, 0, stream>>>(btot, bbase, row_start, bins);
    scatter1_kernel<<<nb1, 256, 0, stream>>>(eidx, eidx + E, eattr, ghist, bbase, buf1, E, nb1, bins);
    bucket2_kernel<<<bins, 256, 0, stream>>>(buf1, bbase, row_start, edges, N);

    // prep
    emb_kernel<<<dim3(18, 2), 128, 0, stream>>>(ee1_0, ee2_0, ee1_1, ee2_1, emb);
    transpose_kernel<<<dim3(128, 4), 256, 0, stream>>>(W1_0, W2_0, W1_1, W2_1, W1t_0);

    // layer 0: xb -> AA -> X2
    aggregate_kernel<<<aggB, 256, 0, stream>>>(xb, row_start, edges, emb, AA, N);
    mlp_kernel<true, false><<<rows64, 256, 0, stream>>>(AA, W1t_0, b1_0, W2t_0, b2_0, X2, N);

    // layer 1: X2 -> AA -> d_out (fp32)
    aggregate_kernel<<<aggB, 256, 0, stream>>>(X2, row_start, edges, emb + 18 * 128, AA, N);
    mlp_kernel<false, true><<<rows64, 256, 0, stream>>>(AA, W1t_1, b1_1, W2t_1, b2_1, d_out, N);
}

// Round 3
// 305.923 us; speedup vs baseline: 1.2809x; 1.0638x over previous
//
#include <hip/hip_runtime.h>

typedef __attribute__((ext_vector_type(8))) short s16x8;
typedef __attribute__((ext_vector_type(4))) float f32x4;
typedef unsigned short u16;
typedef unsigned char u8;
typedef unsigned long long u64;

#define D_FEAT 128
#define TILE1 4096

__device__ __forceinline__ u16 f2bf(float f) {
    unsigned u = __builtin_bit_cast(unsigned, f);
    u = u + 0x7fffu + ((u >> 16) & 1u);   // RNE
    return (u16)(u >> 16);
}

// ---------------- x (fp32) -> bf16 ----------------
__global__ __launch_bounds__(256) void tobf16_kernel(const float4* __restrict__ X,
                                                     u16* __restrict__ out, int n4) {
    int i = blockIdx.x * 256 + threadIdx.x;
    if (i < n4) {
        float4 v = X[i];
        uint2 p;
        p.x = (unsigned)f2bf(v.x) | ((unsigned)f2bf(v.y) << 16);
        p.y = (unsigned)f2bf(v.z) | ((unsigned)f2bf(v.w) << 16);
        *(uint2*)(out + (size_t)i * 4) = p;
    }
}

// ---------------- CSR build via 2-pass bucket sort (LDS atomics only) ----------------
// pass 1a: per-(bucket, block) histogram.  bucket = dst >> 8  (bins = ceil(N/256) <= 256)
__global__ __launch_bounds__(256) void hist1_kernel(const int* __restrict__ dst,
                                                    int* __restrict__ ghist,
                                                    int E, int nb1, int bins) {
    __shared__ int h[256];
    const int t = threadIdx.x;
    h[t] = 0;
    __syncthreads();
    const int base = blockIdx.x * TILE1;
    #pragma unroll
    for (int j = 0; j < TILE1 / 256; ++j) {
        int e = base + j * 256 + t;
        if (e < E) atomicAdd(&h[dst[e] >> 8], 1);
    }
    __syncthreads();
    if (t < bins) ghist[t * nb1 + blockIdx.x] = h[t];
}

// pass 1b-a: one block PER BUCKET.  Wave-scan the bucket's row of nb1 per-block
// counts -> exclusive offsets relative to bucket start (in place) + bucket total.
__global__ __launch_bounds__(256) void scan1a_kernel(int* __restrict__ ghist,
                                                     int* __restrict__ btot, int nb1) {
    __shared__ int wt[4];
    const int t = threadIdx.x, lane = t & 63, wid = t >> 6;
    const int bin = blockIdx.x;
    const int v = (t < nb1) ? ghist[bin * nb1 + t] : 0;
    int s = v;
    #pragma unroll
    for (int off = 1; off < 64; off <<= 1) {
        int u = __shfl_up(s, off, 64);
        if (lane >= off) s += u;
    }
    if (lane == 63) wt[wid] = s;
    __syncthreads();
    int add = 0;
    #pragma unroll
    for (int w = 0; w < 4; ++w) add += (w < wid) ? wt[w] : 0;
    s += add;                                   // inclusive
    if (t < nb1) ghist[bin * nb1 + t] = s - v;  // exclusive, bucket-relative
    if (t == 255) btot[bin] = s;                // bucket total
}

// pass 1b-b: one tiny block.  Scan bucket totals -> exclusive bucket bases.
__global__ __launch_bounds__(256) void scan1b_kernel(const int* __restrict__ btot,
                                                     int* __restrict__ bbase,
                                                     int* __restrict__ row_start, int bins) {
    __shared__ int wt[4];
    const int t = threadIdx.x, lane = t & 63, wid = t >> 6;
    const int v = (t < bins) ? btot[t] : 0;
    int s = v;
    #pragma unroll
    for (int off = 1; off < 64; off <<= 1) {
        int u = __shfl_up(s, off, 64);
        if (lane >= off) s += u;
    }
    if (lane == 63) wt[wid] = s;
    __syncthreads();
    int add = 0;
    #pragma unroll
    for (int w = 0; w < 4; ++w) add += (w < wid) ? wt[w] : 0;
    s += add;                                   // inclusive
    if (t < bins) bbase[t] = s - v;             // exclusive
    if (t == 255) bbase[bins] = s;              // == E sentinel (zeros padded)
    if (t == 0) row_start[0] = 0;
}

// pass 1c: scatter edges into bucket-partitioned u64 buffer.
// rec = (dst << 32) | src | (code << 16).  Positions per block are contiguous runs
// inside each bucket -> write amplification ~3 lines/bucket/block instead of 1 line/edge.
__global__ __launch_bounds__(256) void scatter1_kernel(const int* __restrict__ src,
                                                       const int* __restrict__ dst,
                                                       const int* __restrict__ eattr,
                                                       const int* __restrict__ ghist,
                                                       const int* __restrict__ bbase,
                                                       u64* __restrict__ buf1,
                                                       int E, int nb1, int bins) {
    __shared__ int lofs[256];
    const int t = threadIdx.x;
    if (t < bins) lofs[t] = bbase[t] + ghist[t * nb1 + blockIdx.x];
    __syncthreads();
    const int base = blockIdx.x * TILE1;
    #pragma unroll
    for (int j = 0; j < TILE1 / 256; ++j) {
        int e = base + j * 256 + t;
        if (e < E) {
            int d = dst[e];
            int2 at = ((const int2*)eattr)[e];
            unsigned pay = (unsigned)src[e] | ((unsigned)(at.x * 3 + at.y) << 16);
            int pos = atomicAdd(&lofs[d >> 8], 1);
            buf1[pos] = ((u64)(unsigned)d << 32) | pay;
        }
    }
}

// pass 2: one block per bucket.  Counting sort by local node (dst & 255) inside the
// bucket (all data L2-hot); emits final edges[] run + row_start[] from the block scan.
__global__ __launch_bounds__(256) void bucket2_kernel(const u64* __restrict__ buf1,
                                                      const int* __restrict__ bbase,
                                                      int* __restrict__ row_start,
                                                      unsigned* __restrict__ edges, int N) {
    __shared__ int cnt[256];
    __shared__ int cur[256];
    __shared__ int wt[4];
    const int t = threadIdx.x, lane = t & 63, wid = t >> 6;
    const int bin = blockIdx.x;
    const int lo = bbase[bin], hi = bbase[bin + 1];
    cnt[t] = 0;
    __syncthreads();
    for (int i = lo + t; i < hi; i += 256)
        atomicAdd(&cnt[(int)(buf1[i] >> 32) & 255], 1);
    __syncthreads();
    const int v = cnt[t];
    int s = v;
    #pragma unroll
    for (int off = 1; off < 64; off <<= 1) {
        int u = __shfl_up(s, off, 64);
        if (lane >= off) s += u;
    }
    if (lane == 63) wt[wid] = s;
    __syncthreads();
    int add = 0;
    #pragma unroll
    for (int w = 0; w < 4; ++w) add += (w < wid) ? wt[w] : 0;
    const int incl = s + add;
    const int g = bin * 256 + t;
    if (g < N) row_start[g + 1] = lo + incl;
    cur[t] = incl - v;
    __syncthreads();
    for (int i = lo + t; i < hi; i += 256) {
        u64 rec = buf1[i];
        int loc = atomicAdd(&cur[(int)(rec >> 32) & 255], 1);
        edges[lo + loc] = (unsigned)rec;
    }
}

// ---------------- weight prep: fp32 in -> transposed bf16 out ----------------
__global__ __launch_bounds__(256) void transpose_kernel(const float* __restrict__ W1_0,
                                                        const float* __restrict__ W2_0,
                                                        const float* __restrict__ W1_1,
                                                        const float* __restrict__ W2_1,
                                                        u16* __restrict__ out) {
    int mat = blockIdx.y;
    const float* s = (mat == 0) ? W1_0 : (mat == 1) ? W2_0 : (mat == 2) ? W1_1 : W2_1;
    int K = (mat & 1) ? 256 : 128;
    int Nc = 384 - K;
    u16* d = out + mat * 32768;
    int idx = blockIdx.x * 256 + threadIdx.x;
    int n = idx / K, k = idx - n * K;
    d[idx] = f2bf(s[k * Nc + n]);
}

__global__ __launch_bounds__(128) void emb_kernel(const float* __restrict__ ee1_0,
                                                  const float* __restrict__ ee2_0,
                                                  const float* __restrict__ ee1_1,
                                                  const float* __restrict__ ee2_1,
                                                  float* __restrict__ emb) {
    int code = blockIdx.x;
    int layer = blockIdx.y;
    int d = threadIdx.x;
    int a0 = code / 3, a1 = code - a0 * 3;
    const float* e1 = layer ? ee1_1 : ee1_0;
    const float* e2 = layer ? ee2_1 : ee2_0;
    emb[layer * 18 * 128 + code * 128 + d] = e1[a0 * 128 + d] + e2[a1 * 128 + d];
}

// ---------------- aggregation: one wave per node ----------------
// Lane-parallel edge fetch: one coalesced load covers up to 64 edges of the node.
// readlane broadcasts each edge word to SGPRs -> gather addresses are scalar-base +
// lane*4, all of a node's gathers independent and in flight at once (1 latency round
// per node instead of ceil(d/8) chained rounds).  Padded slots in a partial chunk of
// 16 re-gather edge 0 (L1 hit) and are nullified by a uniform 0/1 mask FMA.
__global__ __launch_bounds__(256) void aggregate_kernel(const u16* __restrict__ X,
                                                        const int* __restrict__ row_start,
                                                        const unsigned* __restrict__ edges,
                                                        const float* __restrict__ emb,
                                                        u16* __restrict__ A, int N) {
    __shared__ float semb[18 * 128];
    for (int i = threadIdx.x; i < 18 * 128; i += 256) semb[i] = emb[i];
    __syncthreads();
    const int node = blockIdx.x * 4 + (threadIdx.x >> 6);
    const int lane = threadIdx.x & 63;
    if (node >= N) return;
    int s = __builtin_amdgcn_readfirstlane(row_start[node]);
    const int e = __builtin_amdgcn_readfirstlane(row_start[node + 1]);
    const float2* sem2 = (const float2*)semb;
    float a0 = 0.f, a1 = 0.f;

    while (s < e) {
        const int take = (e - s < 64) ? (e - s) : 64;             // wave-uniform
        unsigned pl = edges[s + (lane < take ? lane : 0)];        // 1 coalesced load
        #pragma unroll
        for (int c = 0; c < 4; ++c) {
            const int cb = c * 16;
            if (cb < take) {                                      // uniform branch
                unsigned ps[16];
                unsigned xv[16];
                float2 ev[16];
                #pragma unroll
                for (int j = 0; j < 16; ++j)
                    ps[j] = __builtin_amdgcn_readlane(pl, cb + j);  // SGPR broadcast
                #pragma unroll
                for (int j = 0; j < 16; ++j)
                    xv[j] = *(const unsigned*)(X + (ps[j] & 0xFFFFu) * D_FEAT + lane * 2);
                #pragma unroll
                for (int j = 0; j < 16; ++j)
                    ev[j] = sem2[(int)(ps[j] >> 16) * 64 + lane];
                #pragma unroll
                for (int j = 0; j < 16; ++j) {
                    const float m = (cb + j < take) ? 1.f : 0.f;  // uniform mask
                    a0 += m * (__builtin_bit_cast(float, xv[j] << 16) + ev[j].x);
                    a1 += m * (__builtin_bit_cast(float, xv[j] & 0xFFFF0000u) + ev[j].y);
                }
            }
        }
        s += take;
    }
    unsigned outp = (unsigned)f2bf(a0) | ((unsigned)f2bf(a1) << 16);
    *(unsigned*)(A + node * D_FEAT + lane * 2) = outp;
}

// ---------------- fused MLP with LDS-staged weights (round-8 verbatim) ----------------
#define HPAD 264
template <bool RELU2, bool OUTF32>
__global__ __launch_bounds__(256, 1) void mlp_kernel(const u16* __restrict__ A,
                                                     const u16* __restrict__ B1t,
                                                     const float* __restrict__ bias1,
                                                     const u16* __restrict__ B2t,
                                                     const float* __restrict__ bias2,
                                                     void* __restrict__ C, int M) {
    __shared__ __align__(16) u16 wbuf[32768];
    __shared__ __align__(16) u16 hh[4][16][HPAD];
    const int tid = threadIdx.x;
    const int wave = tid >> 6;
    const int lane = tid & 63;
    const int m16 = lane & 15;
    const int quad = lane >> 4;

    const int row0 = blockIdx.x * 64 + wave * 16;
    const int arow = row0 + m16;
    const bool avalid = arow < M;

    // stage W1t (src-linear reads, frag-ordered LDS writes)
    {
        const uint4* src = (const uint4*)B1t;
        #pragma unroll
        for (int i = 0; i < 16; ++i) {
            int s = i * 256 + tid;
            uint4 v = src[s];
            int c = (((s >> 8) * 4 + ((s >> 2) & 3)) << 6) | ((s & 3) << 4) | ((s >> 4) & 15);
            *(uint4*)(wbuf + c * 8) = v;
        }
    }

    s16x8 af[4];
    #pragma unroll
    for (int kb = 0; kb < 4; ++kb) af[kb] = s16x8{};
    if (avalid) {
        #pragma unroll
        for (int kb = 0; kb < 4; ++kb)
            af[kb] = *(const s16x8*)(A + arow * 128 + kb * 32 + quad * 8);
    }
    float b1v[16];
    #pragma unroll
    for (int t = 0; t < 16; ++t) b1v[t] = bias1[t * 16 + m16];

    __syncthreads();

    f32x4 acc[16];
    #pragma unroll
    for (int t = 0; t < 16; ++t) acc[t] = f32x4{0, 0, 0, 0};

    #pragma unroll
    for (int kb = 0; kb < 4; ++kb) {
        #pragma unroll
        for (int t = 0; t < 16; ++t) {
            s16x8 bf = *(const s16x8*)(wbuf + (((((t << 2) | kb) << 6) | lane) * 8));
            acc[t] = __builtin_amdgcn_mfma_f32_16x16x32_bf16(af[kb], bf, acc[t], 0, 0, 0);
        }
    }

    #pragma unroll
    for (int t = 0; t < 16; ++t) {
        const int col = t * 16 + m16;
        #pragma unroll
        for (int r = 0; r < 4; ++r) {
            float v = acc[t][r] + b1v[t];
            v = v > 0.f ? v : 0.f;
            hh[wave][quad * 4 + r][col] = f2bf(v);
        }
    }
    __syncthreads();

    // stage W2t
    {
        const uint4* src = (const uint4*)B2t;
        #pragma unroll
        for (int i = 0; i < 16; ++i) {
            int s = i * 256 + tid;
            uint4 v = src[s];
            int c = (((s >> 9) * 8 + ((s >> 2) & 7)) << 6) | ((s & 3) << 4) | ((s >> 5) & 15);
            *(uint4*)(wbuf + c * 8) = v;
        }
    }
    float b2v[8];
    #pragma unroll
    for (int t = 0; t < 8; ++t) b2v[t] = bias2[t * 16 + m16];

    __syncthreads();

    f32x4 acc2[8];
    #pragma unroll
    for (int t = 0; t < 8; ++t) acc2[t] = f32x4{0, 0, 0, 0};

    #pragma unroll
    for (int kb = 0; kb < 8; ++kb) {
        s16x8 haf = *(const s16x8*)(&hh[wave][m16][kb * 32 + quad * 8]);
        #pragma unroll
        for (int t = 0; t < 8; ++t) {
            s16x8 bf = *(const s16x8*)(wbuf + (((((t << 3) | kb) << 6) | lane) * 8));
            acc2[t] = __builtin_amdgcn_mfma_f32_16x16x32_bf16(haf, bf, acc2[t], 0, 0, 0);
        }
    }

    #pragma unroll
    for (int t = 0; t < 8; ++t) {
        const int col = t * 16 + m16;
        #pragma unroll
        for (int r = 0; r < 4; ++r) {
            const int row = row0 + quad * 4 + r;
            if (row < M) {
                float v = acc2[t][r] + b2v[t];
                if (RELU2) v = v > 0.f ? v : 0.f;
                if (OUTF32) ((float*)C)[row * 128 + col] = v;
                else        ((u16*)C)[row * 128 + col] = f2bf(v);
            }
        }
    }
}

extern "C" void kernel_launch(void* const* d_in, const int* in_sizes, int n_in,
                              void* d_out, int out_size, void* d_ws, size_t ws_size,
                              hipStream_t stream) {
    const int N = in_sizes[0] / D_FEAT;     // 50000
    const int E = in_sizes[1] / 2;          // 800000

    const float* x    = (const float*)d_in[0];
    const int* eidx   = (const int*)d_in[1];
    const int* eattr  = (const int*)d_in[2];
    const float* ee1_0 = (const float*)d_in[3];
    const float* ee2_0 = (const float*)d_in[4];
    const float* W1_0  = (const float*)d_in[5];
    const float* b1_0  = (const float*)d_in[6];
    const float* W2_0  = (const float*)d_in[7];
    const float* b2_0  = (const float*)d_in[8];
    const float* ee1_1 = (const float*)d_in[9];
    const float* ee2_1 = (const float*)d_in[10];
    const float* W1_1  = (const float*)d_in[11];
    const float* b1_1  = (const float*)d_in[12];
    const float* W2_1  = (const float*)d_in[13];
    const float* b2_1  = (const float*)d_in[14];

    const int nb1  = (E + TILE1 - 1) / TILE1;     // 196 pass-1 blocks
    const int bins = (N + 255) / 256;             // 196 buckets

    // workspace
    char* ws = (char*)d_ws;
    size_t off = 0;
    auto alloc = [&](size_t bytes) { size_t o = off; off = (off + bytes + 255) & ~(size_t)255; return o; };
    size_t o_rowstart = alloc((size_t)(N + 1) * 4);
    size_t o_edges    = alloc((size_t)E * 4);
    size_t o_ghist    = alloc((size_t)bins * nb1 * 4);
    size_t o_base     = alloc((size_t)(bins + 1) * 4);
    size_t o_btot     = alloc((size_t)bins * 4);
    size_t o_emb      = alloc(2 * 18 * 128 * 4);
    size_t o_wt       = alloc(4 * 32768 * 2);
    size_t o_aa       = alloc((size_t)N * D_FEAT * 2);

    int*      row_start = (int*)(ws + o_rowstart);
    unsigned* edges     = (unsigned*)(ws + o_edges);
    int*      ghist     = (int*)(ws + o_ghist);
    int*      bbase     = (int*)(ws + o_base);
    int*      btot      = (int*)(ws + o_btot);
    float*    emb       = (float*)(ws + o_emb);
    u16*      W1t_0     = (u16*)(ws + o_wt);
    u16*      W2t_0     = W1t_0 + 32768;
    u16*      W1t_1     = W2t_0 + 32768;
    u16*      W2t_1     = W1t_1 + 32768;
    u16*      AA        = (u16*)(ws + o_aa);
    u64*      buf1      = (u64*)(ws + o_aa);      // aliases AA: E*8 = 6.4MB <= N*128*2, dead before aggregate

    // d_out (fp32, 25.6 MB) staging: front = X2 (bf16 L0 output), back = xb (bf16 x)
    u16* X2 = (u16*)d_out;
    u16* xb = (u16*)d_out + (size_t)N * D_FEAT;

    const int rows64 = (N + 63) / 64;             // 782
    const int aggB = (N + 3) / 4;
    const int n4 = N * D_FEAT / 4;

    tobf16_kernel<<<(n4 + 255) / 256, 256, 0, stream>>>((const float4*)x, xb, n4);

    // CSR build: 2-pass bucket sort, hierarchical scan, no global atomics
    hist1_kernel<<<nb1, 256, 0, stream>>>(eidx + E, ghist, E, nb1, bins);
    scan1a_kernel<<<bins, 256, 0, stream>>>(ghist, btot, nb1);
    scan1b_kernel<<<1, 256, 0, stream>>>(btot, bbase, row_start, bins);
    scatter1_kernel<<<nb1, 256, 0, stream>>>(eidx, eidx + E, eattr, ghist, bbase, buf1, E, nb1, bins);
    bucket2_kernel<<<bins, 256, 0, stream>>>(buf1, bbase, row_start, edges, N);

    // prep
    emb_kernel<<<dim3(18, 2), 128, 0, stream>>>(ee1_0, ee2_0, ee1_1, ee2_1, emb);
    transpose_kernel<<<dim3(128, 4), 256, 0, stream>>>(W1_0, W2_0, W1_1, W2_1, W1t_0);

    // layer 0: xb -> AA -> X2
    aggregate_kernel<<<aggB, 256, 0, stream>>>(xb, row_start, edges, emb, AA, N);
    mlp_kernel<true, false><<<rows64, 256, 0, stream>>>(AA, W1t_0, b1_0, W2t_0, b2_0, X2, N);

    // layer 1: X2 -> AA -> d_out (fp32)
    aggregate_kernel<<<aggB, 256, 0, stream>>>(X2, row_start, edges, emb + 18 * 128, AA, N);
    mlp_kernel<false, true><<<rows64, 256, 0, stream>>>(AA, W1t_1, b1_1, W2t_1, b2_1, d_out, N);
}

// Round 4
// 278.850 us; speedup vs baseline: 1.4053x; 1.0971x over previous
//
#include <hip/hip_runtime.h>

typedef __attribute__((ext_vector_type(8))) short s16x8;
typedef __attribute__((ext_vector_type(4))) float f32x4;
typedef unsigned short u16;
typedef unsigned char u8;
typedef unsigned long long u64;

#define D_FEAT 128
#define TILE1 4096

__device__ __forceinline__ u16 f2bf(float f) {
    unsigned u = __builtin_bit_cast(unsigned, f);
    u = u + 0x7fffu + ((u >> 16) & 1u);   // RNE
    return (u16)(u >> 16);
}

// ---------------- x (fp32) -> bf16 ----------------
__global__ __launch_bounds__(256) void tobf16_kernel(const float4* __restrict__ X,
                                                     u16* __restrict__ out, int n4) {
    int i = blockIdx.x * 256 + threadIdx.x;
    if (i < n4) {
        float4 v = X[i];
        uint2 p;
        p.x = (unsigned)f2bf(v.x) | ((unsigned)f2bf(v.y) << 16);
        p.y = (unsigned)f2bf(v.z) | ((unsigned)f2bf(v.w) << 16);
        *(uint2*)(out + (size_t)i * 4) = p;
    }
}

// ---------------- CSR build via 2-pass bucket sort (LDS atomics only) ----------------
__global__ __launch_bounds__(256) void hist1_kernel(const int* __restrict__ dst,
                                                    int* __restrict__ ghist,
                                                    int E, int nb1, int bins) {
    __shared__ int h[256];
    const int t = threadIdx.x;
    h[t] = 0;
    __syncthreads();
    const int base = blockIdx.x * TILE1;
    #pragma unroll
    for (int j = 0; j < TILE1 / 256; ++j) {
        int e = base + j * 256 + t;
        if (e < E) atomicAdd(&h[dst[e] >> 8], 1);
    }
    __syncthreads();
    if (t < bins) ghist[t * nb1 + blockIdx.x] = h[t];
}

__global__ __launch_bounds__(256) void scan1a_kernel(int* __restrict__ ghist,
                                                     int* __restrict__ btot, int nb1) {
    __shared__ int wt[4];
    const int t = threadIdx.x, lane = t & 63, wid = t >> 6;
    const int bin = blockIdx.x;
    const int v = (t < nb1) ? ghist[bin * nb1 + t] : 0;
    int s = v;
    #pragma unroll
    for (int off = 1; off < 64; off <<= 1) {
        int u = __shfl_up(s, off, 64);
        if (lane >= off) s += u;
    }
    if (lane == 63) wt[wid] = s;
    __syncthreads();
    int add = 0;
    #pragma unroll
    for (int w = 0; w < 4; ++w) add += (w < wid) ? wt[w] : 0;
    s += add;                                   // inclusive
    if (t < nb1) ghist[bin * nb1 + t] = s - v;  // exclusive, bucket-relative
    if (t == 255) btot[bin] = s;                // bucket total
}

__global__ __launch_bounds__(256) void scan1b_kernel(const int* __restrict__ btot,
                                                     int* __restrict__ bbase,
                                                     int* __restrict__ row_start, int bins) {
    __shared__ int wt[4];
    const int t = threadIdx.x, lane = t & 63, wid = t >> 6;
    const int v = (t < bins) ? btot[t] : 0;
    int s = v;
    #pragma unroll
    for (int off = 1; off < 64; off <<= 1) {
        int u = __shfl_up(s, off, 64);
        if (lane >= off) s += u;
    }
    if (lane == 63) wt[wid] = s;
    __syncthreads();
    int add = 0;
    #pragma unroll
    for (int w = 0; w < 4; ++w) add += (w < wid) ? wt[w] : 0;
    s += add;                                   // inclusive
    if (t < bins) bbase[t] = s - v;             // exclusive
    if (t == 255) bbase[bins] = s;              // == E sentinel
    if (t == 0) row_start[0] = 0;
}

__global__ __launch_bounds__(256) void scatter1_kernel(const int* __restrict__ src,
                                                       const int* __restrict__ dst,
                                                       const int* __restrict__ eattr,
                                                       const int* __restrict__ ghist,
                                                       const int* __restrict__ bbase,
                                                       u64* __restrict__ buf1,
                                                       int E, int nb1, int bins) {
    __shared__ int lofs[256];
    const int t = threadIdx.x;
    if (t < bins) lofs[t] = bbase[t] + ghist[t * nb1 + blockIdx.x];
    __syncthreads();
    const int base = blockIdx.x * TILE1;
    #pragma unroll
    for (int j = 0; j < TILE1 / 256; ++j) {
        int e = base + j * 256 + t;
        if (e < E) {
            int d = dst[e];
            int2 at = ((const int2*)eattr)[e];
            unsigned pay = (unsigned)src[e] | ((unsigned)(at.x * 3 + at.y) << 16);
            int pos = atomicAdd(&lofs[d >> 8], 1);
            buf1[pos] = ((u64)(unsigned)d << 32) | pay;
        }
    }
}

__global__ __launch_bounds__(256) void bucket2_kernel(const u64* __restrict__ buf1,
                                                      const int* __restrict__ bbase,
                                                      int* __restrict__ row_start,
                                                      unsigned* __restrict__ edges, int N) {
    __shared__ int cnt[256];
    __shared__ int cur[256];
    __shared__ int wt[4];
    const int t = threadIdx.x, lane = t & 63, wid = t >> 6;
    const int bin = blockIdx.x;
    const int lo = bbase[bin], hi = bbase[bin + 1];
    cnt[t] = 0;
    __syncthreads();
    for (int i = lo + t; i < hi; i += 256)
        atomicAdd(&cnt[(int)(buf1[i] >> 32) & 255], 1);
    __syncthreads();
    const int v = cnt[t];
    int s = v;
    #pragma unroll
    for (int off = 1; off < 64; off <<= 1) {
        int u = __shfl_up(s, off, 64);
        if (lane >= off) s += u;
    }
    if (lane == 63) wt[wid] = s;
    __syncthreads();
    int add = 0;
    #pragma unroll
    for (int w = 0; w < 4; ++w) add += (w < wid) ? wt[w] : 0;
    const int incl = s + add;
    const int g = bin * 256 + t;
    if (g < N) row_start[g + 1] = lo + incl;
    cur[t] = incl - v;
    __syncthreads();
    for (int i = lo + t; i < hi; i += 256) {
        u64 rec = buf1[i];
        int loc = atomicAdd(&cur[(int)(rec >> 32) & 255], 1);
        edges[lo + loc] = (unsigned)rec;
    }
}

// ---------------- weight prep: fp32 in -> transposed bf16 out ----------------
__global__ __launch_bounds__(256) void transpose_kernel(const float* __restrict__ W1_0,
                                                        const float* __restrict__ W2_0,
                                                        const float* __restrict__ W1_1,
                                                        const float* __restrict__ W2_1,
                                                        u16* __restrict__ out) {
    int mat = blockIdx.y;
    const float* s = (mat == 0) ? W1_0 : (mat == 1) ? W2_0 : (mat == 2) ? W1_1 : W2_1;
    int K = (mat & 1) ? 256 : 128;
    int Nc = 384 - K;
    u16* d = out + mat * 32768;
    int idx = blockIdx.x * 256 + threadIdx.x;
    int n = idx / K, k = idx - n * K;
    d[idx] = f2bf(s[k * Nc + n]);
}

__global__ __launch_bounds__(128) void emb_kernel(const float* __restrict__ ee1_0,
                                                  const float* __restrict__ ee2_0,
                                                  const float* __restrict__ ee1_1,
                                                  const float* __restrict__ ee2_1,
                                                  float* __restrict__ emb) {
    int code = blockIdx.x;
    int layer = blockIdx.y;
    int d = threadIdx.x;
    int a0 = code / 3, a1 = code - a0 * 3;
    const float* e1 = layer ? ee1_1 : ee1_0;
    const float* e2 = layer ? ee2_1 : ee2_0;
    emb[layer * 18 * 128 + code * 128 + d] = e1[a0 * 128 + d] + e2[a1 * 128 + d];
}

// ---------------- aggregation: one wave per node, readlane-broadcast gathers ----------------
// Full 16-chunks take the unmasked path (pure fadd); only the single partial chunk
// pays the 0/1-mask FMA.
__global__ __launch_bounds__(256) void aggregate_kernel(const u16* __restrict__ X,
                                                        const int* __restrict__ row_start,
                                                        const unsigned* __restrict__ edges,
                                                        const float* __restrict__ emb,
                                                        u16* __restrict__ A, int N) {
    __shared__ float semb[18 * 128];
    for (int i = threadIdx.x; i < 18 * 128; i += 256) semb[i] = emb[i];
    __syncthreads();
    const int node = blockIdx.x * 4 + (threadIdx.x >> 6);
    const int lane = threadIdx.x & 63;
    if (node >= N) return;
    int s = __builtin_amdgcn_readfirstlane(row_start[node]);
    const int e = __builtin_amdgcn_readfirstlane(row_start[node + 1]);
    const float2* sem2 = (const float2*)semb;
    float a0 = 0.f, a1 = 0.f;

    while (s < e) {
        const int take = (e - s < 64) ? (e - s) : 64;             // wave-uniform
        unsigned pl = edges[s + (lane < take ? lane : 0)];        // 1 coalesced load
        #pragma unroll
        for (int c = 0; c < 4; ++c) {
            const int cb = c * 16;
            if (cb + 16 <= take) {                                // full chunk, no mask
                unsigned ps[16];
                unsigned xv[16];
                float2 ev[16];
                #pragma unroll
                for (int j = 0; j < 16; ++j)
                    ps[j] = __builtin_amdgcn_readlane(pl, cb + j);
                #pragma unroll
                for (int j = 0; j < 16; ++j)
                    xv[j] = *(const unsigned*)(X + (ps[j] & 0xFFFFu) * D_FEAT + lane * 2);
                #pragma unroll
                for (int j = 0; j < 16; ++j)
                    ev[j] = sem2[(int)(ps[j] >> 16) * 64 + lane];
                #pragma unroll
                for (int j = 0; j < 16; ++j) {
                    a0 += __builtin_bit_cast(float, xv[j] << 16) + ev[j].x;
                    a1 += __builtin_bit_cast(float, xv[j] & 0xFFFF0000u) + ev[j].y;
                }
            } else if (cb < take) {                               // partial chunk, masked
                unsigned ps[16];
                unsigned xv[16];
                float2 ev[16];
                #pragma unroll
                for (int j = 0; j < 16; ++j)
                    ps[j] = __builtin_amdgcn_readlane(pl, cb + j);
                #pragma unroll
                for (int j = 0; j < 16; ++j)
                    xv[j] = *(const unsigned*)(X + (ps[j] & 0xFFFFu) * D_FEAT + lane * 2);
                #pragma unroll
                for (int j = 0; j < 16; ++j)
                    ev[j] = sem2[(int)(ps[j] >> 16) * 64 + lane];
                #pragma unroll
                for (int j = 0; j < 16; ++j) {
                    const float m = (cb + j < take) ? 1.f : 0.f;
                    a0 += m * (__builtin_bit_cast(float, xv[j] << 16) + ev[j].x);
                    a1 += m * (__builtin_bit_cast(float, xv[j] & 0xFFFF0000u) + ev[j].y);
                }
            }
        }
        s += take;
    }
    unsigned outp = (unsigned)f2bf(a0) | ((unsigned)f2bf(a1) << 16);
    *(unsigned*)(A + node * D_FEAT + lane * 2) = outp;
}

// ---------------- persistent-weight fused MLP ----------------
// 160 KB dynamic LDS: W1t (64KB) + W2t (64KB) staged ONCE per block; hh (32KB,
// XOR-swizzled, no pad) reused per tile.  Grid = 256 blocks (1/CU); each block
// strides over row-tiles of 64 with A-frag prefetch under GEMM2.
template <bool RELU2, bool OUTF32>
__global__ __launch_bounds__(256, 1) void mlp_kernel(const u16* __restrict__ A,
                                                     const u16* __restrict__ B1t,
                                                     const float* __restrict__ bias1,
                                                     const u16* __restrict__ B2t,
                                                     const float* __restrict__ bias2,
                                                     void* __restrict__ C, int M, int nt) {
    extern __shared__ __align__(16) u16 lds[];
    u16* w1 = lds;              // 32768 u16
    u16* w2 = lds + 32768;      // 32768 u16
    u16* hh = lds + 65536;      // 16384 u16 = [4 waves][16 rows][256 cols], swizzled
    const int tid = threadIdx.x;
    const int wave = tid >> 6;
    const int lane = tid & 63;
    const int m16 = lane & 15;
    const int quad = lane >> 4;

    // stage W1t + W2t once (src-linear reads, frag-ordered LDS writes)
    {
        const uint4* src1 = (const uint4*)B1t;
        const uint4* src2 = (const uint4*)B2t;
        #pragma unroll
        for (int i = 0; i < 16; ++i) {
            int s = i * 256 + tid;
            uint4 v = src1[s];
            int c = (((s >> 8) * 4 + ((s >> 2) & 3)) << 6) | ((s & 3) << 4) | ((s >> 4) & 15);
            *(uint4*)(w1 + c * 8) = v;
        }
        #pragma unroll
        for (int i = 0; i < 16; ++i) {
            int s = i * 256 + tid;
            uint4 v = src2[s];
            int c = (((s >> 9) * 8 + ((s >> 2) & 7)) << 6) | ((s & 3) << 4) | ((s >> 5) & 15);
            *(uint4*)(w2 + c * 8) = v;
        }
    }
    float b1v[16];
    #pragma unroll
    for (int t = 0; t < 16; ++t) b1v[t] = bias1[t * 16 + m16];
    float b2v[8];
    #pragma unroll
    for (int t = 0; t < 8; ++t) b2v[t] = bias2[t * 16 + m16];

    // hh addressing: u16 idx = wave*4096 + row*256 + col, XOR-swizzled by (row&7)<<3
    const int hbase = wave * 4096;

    // preload first tile's A-frags
    int tile = blockIdx.x;
    s16x8 af[4];
    #pragma unroll
    for (int kb = 0; kb < 4; ++kb) af[kb] = s16x8{};
    if (tile < nt) {
        const int arow = tile * 64 + wave * 16 + m16;
        if (arow < M) {
            #pragma unroll
            for (int kb = 0; kb < 4; ++kb)
                af[kb] = *(const s16x8*)(A + (size_t)arow * 128 + kb * 32 + quad * 8);
        }
    }

    __syncthreads();

    for (; tile < nt; tile += 256) {
        const int row0 = tile * 64 + wave * 16;

        // GEMM1: 16 rows x 256 cols
        f32x4 acc[16];
        #pragma unroll
        for (int t = 0; t < 16; ++t) acc[t] = f32x4{0, 0, 0, 0};
        #pragma unroll
        for (int kb = 0; kb < 4; ++kb) {
            #pragma unroll
            for (int t = 0; t < 16; ++t) {
                s16x8 bf = *(const s16x8*)(w1 + (((((t << 2) | kb) << 6) | lane) * 8));
                acc[t] = __builtin_amdgcn_mfma_f32_16x16x32_bf16(af[kb], bf, acc[t], 0, 0, 0);
            }
        }

        // prefetch next tile's A-frags (hidden under hh-write + GEMM2)
        const int ntile = tile + 256;
        s16x8 afn[4];
        #pragma unroll
        for (int kb = 0; kb < 4; ++kb) afn[kb] = s16x8{};
        if (ntile < nt) {
            const int arow = ntile * 64 + wave * 16 + m16;
            if (arow < M) {
                #pragma unroll
                for (int kb = 0; kb < 4; ++kb)
                    afn[kb] = *(const s16x8*)(A + (size_t)arow * 128 + kb * 32 + quad * 8);
            }
        }

        // relu + bf16 -> hh (swizzled scatter)
        #pragma unroll
        for (int t = 0; t < 16; ++t) {
            const int col = t * 16 + m16;
            #pragma unroll
            for (int r = 0; r < 4; ++r) {
                const int row = quad * 4 + r;
                float v = acc[t][r] + b1v[t];
                v = v > 0.f ? v : 0.f;
                hh[(hbase + row * 256 + col) ^ ((row & 7) << 3)] = f2bf(v);
            }
        }
        __syncthreads();

        // GEMM2: 16 rows x 128 cols from hh
        f32x4 acc2[8];
        #pragma unroll
        for (int t = 0; t < 8; ++t) acc2[t] = f32x4{0, 0, 0, 0};
        #pragma unroll
        for (int kb = 0; kb < 8; ++kb) {
            s16x8 haf = *(const s16x8*)(hh + ((hbase + m16 * 256 + kb * 32 + quad * 8) ^ ((m16 & 7) << 3)));
            #pragma unroll
            for (int t = 0; t < 8; ++t) {
                s16x8 bf = *(const s16x8*)(w2 + (((((t << 3) | kb) << 6) | lane) * 8));
                acc2[t] = __builtin_amdgcn_mfma_f32_16x16x32_bf16(haf, bf, acc2[t], 0, 0, 0);
            }
        }

        // epilogue
        #pragma unroll
        for (int t = 0; t < 8; ++t) {
            const int col = t * 16 + m16;
            #pragma unroll
            for (int r = 0; r < 4; ++r) {
                const int row = row0 + quad * 4 + r;
                if (row < M) {
                    float v = acc2[t][r] + b2v[t];
                    if (RELU2) v = v > 0.f ? v : 0.f;
                    if (OUTF32) ((float*)C)[(size_t)row * 128 + col] = v;
                    else        ((u16*)C)[(size_t)row * 128 + col] = f2bf(v);
                }
            }
        }
        __syncthreads();   // hh consumed before next tile overwrites it

        #pragma unroll
        for (int kb = 0; kb < 4; ++kb) af[kb] = afn[kb];
    }
}

extern "C" void kernel_launch(void* const* d_in, const int* in_sizes, int n_in,
                              void* d_out, int out_size, void* d_ws, size_t ws_size,
                              hipStream_t stream) {
    const int N = in_sizes[0] / D_FEAT;     // 50000
    const int E = in_sizes[1] / 2;          // 800000

    const float* x    = (const float*)d_in[0];
    const int* eidx   = (const int*)d_in[1];
    const int* eattr  = (const int*)d_in[2];
    const float* ee1_0 = (const float*)d_in[3];
    const float* ee2_0 = (const float*)d_in[4];
    const float* W1_0  = (const float*)d_in[5];
    const float* b1_0  = (const float*)d_in[6];
    const float* W2_0  = (const float*)d_in[7];
    const float* b2_0  = (const float*)d_in[8];
    const float* ee1_1 = (const float*)d_in[9];
    const float* ee2_1 = (const float*)d_in[10];
    const float* W1_1  = (const float*)d_in[11];
    const float* b1_1  = (const float*)d_in[12];
    const float* W2_1  = (const float*)d_in[13];
    const float* b2_1  = (const float*)d_in[14];

    const int nb1  = (E + TILE1 - 1) / TILE1;     // 196 pass-1 blocks
    const int bins = (N + 255) / 256;             // 196 buckets

    // workspace
    char* ws = (char*)d_ws;
    size_t off = 0;
    auto alloc = [&](size_t bytes) { size_t o = off; off = (off + bytes + 255) & ~(size_t)255; return o; };
    size_t o_rowstart = alloc((size_t)(N + 1) * 4);
    size_t o_edges    = alloc((size_t)E * 4);
    size_t o_ghist    = alloc((size_t)bins * nb1 * 4);
    size_t o_base     = alloc((size_t)(bins + 1) * 4);
    size_t o_btot     = alloc((size_t)bins * 4);
    size_t o_emb      = alloc(2 * 18 * 128 * 4);
    size_t o_wt       = alloc(4 * 32768 * 2);
    size_t o_aa       = alloc((size_t)N * D_FEAT * 2);

    int*      row_start = (int*)(ws + o_rowstart);
    unsigned* edges     = (unsigned*)(ws + o_edges);
    int*      ghist     = (int*)(ws + o_ghist);
    int*      bbase     = (int*)(ws + o_base);
    int*      btot      = (int*)(ws + o_btot);
    float*    emb       = (float*)(ws + o_emb);
    u16*      W1t_0     = (u16*)(ws + o_wt);
    u16*      W2t_0     = W1t_0 + 32768;
    u16*      W1t_1     = W2t_0 + 32768;
    u16*      W2t_1     = W1t_1 + 32768;
    u16*      AA        = (u16*)(ws + o_aa);
    u64*      buf1      = (u64*)(ws + o_aa);      // aliases AA (dead before aggregate)

    // d_out (fp32, 25.6 MB) staging: front = X2 (bf16 L0 output), back = xb (bf16 x)
    u16* X2 = (u16*)d_out;
    u16* xb = (u16*)d_out + (size_t)N * D_FEAT;

    const int nt = (N + 63) / 64;                 // 782 row tiles
    const int aggB = (N + 3) / 4;
    const int n4 = N * D_FEAT / 4;
    const int LDS_MLP = 163840;                   // 160 KB

    static bool attr_done = false;
    if (!attr_done) {
        hipFuncSetAttribute((const void*)mlp_kernel<true, false>,
                            hipFuncAttributeMaxDynamicSharedMemorySize, LDS_MLP);
        hipFuncSetAttribute((const void*)mlp_kernel<false, true>,
                            hipFuncAttributeMaxDynamicSharedMemorySize, LDS_MLP);
        attr_done = true;
    }

    tobf16_kernel<<<(n4 + 255) / 256, 256, 0, stream>>>((const float4*)x, xb, n4);

    // CSR build: 2-pass bucket sort, hierarchical scan, no global atomics
    hist1_kernel<<<nb1, 256, 0, stream>>>(eidx + E, ghist, E, nb1, bins);
    scan1a_kernel<<<bins, 256, 0, stream>>>(ghist, btot, nb1);
    scan1b_kernel<<<1, 256, 0, stream>>>(btot, bbase, row_start, bins);
    scatter1_kernel<<<nb1, 256, 0, stream>>>(eidx, eidx + E, eattr, ghist, bbase, buf1, E, nb1, bins);
    bucket2_kernel<<<bins, 256, 0, stream>>>(buf1, bbase, row_start, edges, N);

    // prep
    emb_kernel<<<dim3(18, 2), 128, 0, stream>>>(ee1_0, ee2_0, ee1_1, ee2_1, emb);
    transpose_kernel<<<dim3(128, 4), 256, 0, stream>>>(W1_0, W2_0, W1_1, W2_1, W1t_0);

    // layer 0: xb -> AA -> X2
    aggregate_kernel<<<aggB, 256, 0, stream>>>(xb, row_start, edges, emb, AA, N);
    mlp_kernel<true, false><<<256, 256, LDS_MLP, stream>>>(AA, W1t_0, b1_0, W2t_0, b2_0, X2, N, nt);

    // layer 1: X2 -> AA -> d_out (fp32)
    aggregate_kernel<<<aggB, 256, 0, stream>>>(X2, row_start, edges, emb + 18 * 128, AA, N);
    mlp_kernel<false, true><<<256, 256, LDS_MLP, stream>>>(AA, W1t_1, b1_1, W2t_1, b2_1, d_out, N, nt);
}

// Round 5
// 275.738 us; speedup vs baseline: 1.4211x; 1.0113x over previous
//
#include <hip/hip_runtime.h>

typedef __attribute__((ext_vector_type(8))) short s16x8;
typedef __attribute__((ext_vector_type(4))) float f32x4;
typedef unsigned short u16;
typedef unsigned char u8;
typedef unsigned long long u64;

#define D_FEAT 128
#define TILE1 4096

__device__ __forceinline__ u16 f2bf(float f) {
    unsigned u = __builtin_bit_cast(unsigned, f);
    u = u + 0x7fffu + ((u >> 16) & 1u);   // RNE
    return (u16)(u >> 16);
}

// ---------------- x (fp32) -> bf16 ----------------
__global__ __launch_bounds__(256) void tobf16_kernel(const float4* __restrict__ X,
                                                     u16* __restrict__ out, int n4) {
    int i = blockIdx.x * 256 + threadIdx.x;
    if (i < n4) {
        float4 v = X[i];
        uint2 p;
        p.x = (unsigned)f2bf(v.x) | ((unsigned)f2bf(v.y) << 16);
        p.y = (unsigned)f2bf(v.z) | ((unsigned)f2bf(v.w) << 16);
        *(uint2*)(out + (size_t)i * 4) = p;
    }
}

// ---------------- CSR build via 2-pass bucket sort (LDS atomics only) ----------------
__global__ __launch_bounds__(256) void hist1_kernel(const int* __restrict__ dst,
                                                    int* __restrict__ ghist,
                                                    int E, int nb1, int bins) {
    __shared__ int h[256];
    const int t = threadIdx.x;
    h[t] = 0;
    __syncthreads();
    const int base = blockIdx.x * TILE1;
    #pragma unroll
    for (int j = 0; j < TILE1 / 256; ++j) {
        int e = base + j * 256 + t;
        if (e < E) atomicAdd(&h[dst[e] >> 8], 1);
    }
    __syncthreads();
    if (t < bins) ghist[t * nb1 + blockIdx.x] = h[t];
}

__global__ __launch_bounds__(256) void scan1a_kernel(int* __restrict__ ghist,
                                                     int* __restrict__ btot, int nb1) {
    __shared__ int wt[4];
    const int t = threadIdx.x, lane = t & 63, wid = t >> 6;
    const int bin = blockIdx.x;
    const int v = (t < nb1) ? ghist[bin * nb1 + t] : 0;
    int s = v;
    #pragma unroll
    for (int off = 1; off < 64; off <<= 1) {
        int u = __shfl_up(s, off, 64);
        if (lane >= off) s += u;
    }
    if (lane == 63) wt[wid] = s;
    __syncthreads();
    int add = 0;
    #pragma unroll
    for (int w = 0; w < 4; ++w) add += (w < wid) ? wt[w] : 0;
    s += add;                                   // inclusive
    if (t < nb1) ghist[bin * nb1 + t] = s - v;  // exclusive, bucket-relative
    if (t == 255) btot[bin] = s;                // bucket total
}

__global__ __launch_bounds__(256) void scan1b_kernel(const int* __restrict__ btot,
                                                     int* __restrict__ bbase,
                                                     int* __restrict__ row_start, int bins) {
    __shared__ int wt[4];
    const int t = threadIdx.x, lane = t & 63, wid = t >> 6;
    const int v = (t < bins) ? btot[t] : 0;
    int s = v;
    #pragma unroll
    for (int off = 1; off < 64; off <<= 1) {
        int u = __shfl_up(s, off, 64);
        if (lane >= off) s += u;
    }
    if (lane == 63) wt[wid] = s;
    __syncthreads();
    int add = 0;
    #pragma unroll
    for (int w = 0; w < 4; ++w) add += (w < wid) ? wt[w] : 0;
    s += add;                                   // inclusive
    if (t < bins) bbase[t] = s - v;             // exclusive
    if (t == 255) bbase[bins] = s;              // == E sentinel
    if (t == 0) row_start[0] = 0;
}

__global__ __launch_bounds__(256) void scatter1_kernel(const int* __restrict__ src,
                                                       const int* __restrict__ dst,
                                                       const int* __restrict__ eattr,
                                                       const int* __restrict__ ghist,
                                                       const int* __restrict__ bbase,
                                                       u64* __restrict__ buf1,
                                                       int E, int nb1, int bins) {
    __shared__ int lofs[256];
    const int t = threadIdx.x;
    if (t < bins) lofs[t] = bbase[t] + ghist[t * nb1 + blockIdx.x];
    __syncthreads();
    const int base = blockIdx.x * TILE1;
    #pragma unroll
    for (int j = 0; j < TILE1 / 256; ++j) {
        int e = base + j * 256 + t;
        if (e < E) {
            int d = dst[e];
            int2 at = ((const int2*)eattr)[e];
            unsigned pay = (unsigned)src[e] | ((unsigned)(at.x * 3 + at.y) << 16);
            int pos = atomicAdd(&lofs[d >> 8], 1);
            buf1[pos] = ((u64)(unsigned)d << 32) | pay;
        }
    }
}

// pass 2: counting sort within bucket + per-node code histogram (18 codes).
// counts packed as u8 x18 into 5 u32 words per node.
__global__ __launch_bounds__(256) void bucket2_kernel(const u64* __restrict__ buf1,
                                                      const int* __restrict__ bbase,
                                                      int* __restrict__ row_start,
                                                      unsigned* __restrict__ edges,
                                                      unsigned* __restrict__ countsw, int N) {
    __shared__ int cnt[256];
    __shared__ int cur[256];
    __shared__ int wt[4];
    __shared__ unsigned ccnt[256 * 18];
    const int t = threadIdx.x, lane = t & 63, wid = t >> 6;
    const int bin = blockIdx.x;
    const int lo = bbase[bin], hi = bbase[bin + 1];
    cnt[t] = 0;
    for (int i = t; i < 256 * 18; i += 256) ccnt[i] = 0;
    __syncthreads();
    for (int i = lo + t; i < hi; i += 256)
        atomicAdd(&cnt[(int)(buf1[i] >> 32) & 255], 1);
    __syncthreads();
    const int v = cnt[t];
    int s = v;
    #pragma unroll
    for (int off = 1; off < 64; off <<= 1) {
        int u = __shfl_up(s, off, 64);
        if (lane >= off) s += u;
    }
    if (lane == 63) wt[wid] = s;
    __syncthreads();
    int add = 0;
    #pragma unroll
    for (int w = 0; w < 4; ++w) add += (w < wid) ? wt[w] : 0;
    const int incl = s + add;
    const int g = bin * 256 + t;
    if (g < N) row_start[g + 1] = lo + incl;
    cur[t] = incl - v;
    __syncthreads();
    for (int i = lo + t; i < hi; i += 256) {
        u64 rec = buf1[i];
        const int local = (int)(rec >> 32) & 255;
        int loc = atomicAdd(&cur[local], 1);
        edges[lo + loc] = (unsigned)rec;
        atomicAdd(&ccnt[local * 18 + ((unsigned)rec >> 16)], 1);
    }
    __syncthreads();
    if (g < N) {
        unsigned w[5] = {0, 0, 0, 0, 0};
        #pragma unroll
        for (int c = 0; c < 18; ++c)
            w[c >> 2] |= ccnt[t * 18 + c] << (8 * (c & 3));
        #pragma unroll
        for (int k = 0; k < 5; ++k)
            countsw[(size_t)g * 5 + k] = w[k];
    }
}

// ---------------- weight prep: fp32 in -> transposed bf16 out ----------------
__global__ __launch_bounds__(256) void transpose_kernel(const float* __restrict__ W1_0,
                                                        const float* __restrict__ W2_0,
                                                        const float* __restrict__ W1_1,
                                                        const float* __restrict__ W2_1,
                                                        u16* __restrict__ out) {
    int mat = blockIdx.y;
    const float* s = (mat == 0) ? W1_0 : (mat == 1) ? W2_0 : (mat == 2) ? W1_1 : W2_1;
    int K = (mat & 1) ? 256 : 128;
    int Nc = 384 - K;
    u16* d = out + mat * 32768;
    int idx = blockIdx.x * 256 + threadIdx.x;
    int n = idx / K, k = idx - n * K;
    d[idx] = f2bf(s[k * Nc + n]);
}

__global__ __launch_bounds__(128) void emb_kernel(const float* __restrict__ ee1_0,
                                                  const float* __restrict__ ee2_0,
                                                  const float* __restrict__ ee1_1,
                                                  const float* __restrict__ ee2_1,
                                                  float* __restrict__ emb) {
    int code = blockIdx.x;
    int layer = blockIdx.y;
    int d = threadIdx.x;
    int a0 = code / 3, a1 = code - a0 * 3;
    const float* e1 = layer ? ee1_1 : ee1_0;
    const float* e2 = layer ? ee2_1 : ee2_0;
    emb[layer * 18 * 128 + code * 128 + d] = e1[a0 * 128 + d] + e2[a1 * 128 + d];
}

// ---------------- aggregation: one wave per node ----------------
// Edge loop: readlane-broadcast gathers, 4 VALU/edge, no per-edge LDS.
// Edge-embedding term folded into per-node epilogue via code counts:
//   aggr += sum_c count_c(node) * emb[c]   (18 broadcast-count FMAs)
__global__ __launch_bounds__(256) void aggregate_kernel(const u16* __restrict__ X,
                                                        const int* __restrict__ row_start,
                                                        const unsigned* __restrict__ edges,
                                                        const float* __restrict__ emb,
                                                        const unsigned* __restrict__ countsw,
                                                        u16* __restrict__ A, int N) {
    __shared__ float semb[18 * 128];
    for (int i = threadIdx.x; i < 18 * 128; i += 256) semb[i] = emb[i];
    __syncthreads();
    const int node = blockIdx.x * 4 + (threadIdx.x >> 6);
    const int lane = threadIdx.x & 63;
    if (node >= N) return;

    // issue count loads early (uniform address -> broadcast), hidden under edge loop
    unsigned cw[5];
    #pragma unroll
    for (int k = 0; k < 5; ++k) cw[k] = countsw[(size_t)node * 5 + k];

    int s = __builtin_amdgcn_readfirstlane(row_start[node]);
    const int e = __builtin_amdgcn_readfirstlane(row_start[node + 1]);
    const float2* sem2 = (const float2*)semb;
    float a0 = 0.f, a1 = 0.f;

    while (s < e) {
        const int take = (e - s < 64) ? (e - s) : 64;             // wave-uniform
        unsigned pl = edges[s + (lane < take ? lane : 0)];        // 1 coalesced load
        #pragma unroll
        for (int c = 0; c < 4; ++c) {
            const int cb = c * 16;
            if (cb < take) {                                      // uniform branch
                unsigned ps[16];
                unsigned xv[16];
                #pragma unroll
                for (int j = 0; j < 16; ++j)
                    ps[j] = __builtin_amdgcn_readlane(pl, cb + j);  // SGPR broadcast
                #pragma unroll
                for (int j = 0; j < 16; ++j)
                    xv[j] = *(const unsigned*)(X + (ps[j] & 0xFFFFu) * D_FEAT + lane * 2);
                #pragma unroll
                for (int j = 0; j < 16; ++j) {
                    const float m = (cb + j < take) ? 1.f : 0.f;  // uniform mask
                    a0 += m * __builtin_bit_cast(float, xv[j] << 16);
                    a1 += m * __builtin_bit_cast(float, xv[j] & 0xFFFF0000u);
                }
            }
        }
        s += take;
    }

    // epilogue: + sum_c count_c * emb[c][dim]
    #pragma unroll
    for (int w = 0; w < 5; ++w) {
        #pragma unroll
        for (int b = 0; b < 4; ++b) {
            const int code = w * 4 + b;
            if (code < 18) {
                const float cf = (float)((cw[w] >> (8 * b)) & 255u);
                float2 ev = sem2[code * 64 + lane];
                a0 += cf * ev.x;
                a1 += cf * ev.y;
            }
        }
    }

    unsigned outp = (unsigned)f2bf(a0) | ((unsigned)f2bf(a1) << 16);
    *(unsigned*)(A + node * D_FEAT + lane * 2) = outp;
}

// ---------------- persistent-weight fused MLP ----------------
// 160 KB dynamic LDS: W1t (64KB) + W2t (64KB) staged ONCE per block; hh (32KB,
// XOR-swizzled, no pad) reused per tile.  Grid = 256 blocks (1/CU); each block
// strides over row-tiles of 64 with A-frag prefetch under GEMM2.
template <bool RELU2, bool OUTF32>
__global__ __launch_bounds__(256, 1) void mlp_kernel(const u16* __restrict__ A,
                                                     const u16* __restrict__ B1t,
                                                     const float* __restrict__ bias1,
                                                     const u16* __restrict__ B2t,
                                                     const float* __restrict__ bias2,
                                                     void* __restrict__ C, int M, int nt) {
    extern __shared__ __align__(16) u16 lds[];
    u16* w1 = lds;              // 32768 u16
    u16* w2 = lds + 32768;      // 32768 u16
    u16* hh = lds + 65536;      // 16384 u16 = [4 waves][16 rows][256 cols], swizzled
    const int tid = threadIdx.x;
    const int wave = tid >> 6;
    const int lane = tid & 63;
    const int m16 = lane & 15;
    const int quad = lane >> 4;

    // stage W1t + W2t once (src-linear reads, frag-ordered LDS writes)
    {
        const uint4* src1 = (const uint4*)B1t;
        const uint4* src2 = (const uint4*)B2t;
        #pragma unroll
        for (int i = 0; i < 16; ++i) {
            int s = i * 256 + tid;
            uint4 v = src1[s];
            int c = (((s >> 8) * 4 + ((s >> 2) & 3)) << 6) | ((s & 3) << 4) | ((s >> 4) & 15);
            *(uint4*)(w1 + c * 8) = v;
        }
        #pragma unroll
        for (int i = 0; i < 16; ++i) {
            int s = i * 256 + tid;
            uint4 v = src2[s];
            int c = (((s >> 9) * 8 + ((s >> 2) & 7)) << 6) | ((s & 3) << 4) | ((s >> 5) & 15);
            *(uint4*)(w2 + c * 8) = v;
        }
    }
    float b1v[16];
    #pragma unroll
    for (int t = 0; t < 16; ++t) b1v[t] = bias1[t * 16 + m16];
    float b2v[8];
    #pragma unroll
    for (int t = 0; t < 8; ++t) b2v[t] = bias2[t * 16 + m16];

    // hh addressing: u16 idx = wave*4096 + row*256 + col, XOR-swizzled by (row&7)<<3
    const int hbase = wave * 4096;

    // preload first tile's A-frags
    int tile = blockIdx.x;
    s16x8 af[4];
    #pragma unroll
    for (int kb = 0; kb < 4; ++kb) af[kb] = s16x8{};
    if (tile < nt) {
        const int arow = tile * 64 + wave * 16 + m16;
        if (arow < M) {
            #pragma unroll
            for (int kb = 0; kb < 4; ++kb)
                af[kb] = *(const s16x8*)(A + (size_t)arow * 128 + kb * 32 + quad * 8);
        }
    }

    __syncthreads();

    for (; tile < nt; tile += 256) {
        const int row0 = tile * 64 + wave * 16;

        // GEMM1: 16 rows x 256 cols
        f32x4 acc[16];
        #pragma unroll
        for (int t = 0; t < 16; ++t) acc[t] = f32x4{0, 0, 0, 0};
        #pragma unroll
        for (int kb = 0; kb < 4; ++kb) {
            #pragma unroll
            for (int t = 0; t < 16; ++t) {
                s16x8 bf = *(const s16x8*)(w1 + (((((t << 2) | kb) << 6) | lane) * 8));
                acc[t] = __builtin_amdgcn_mfma_f32_16x16x32_bf16(af[kb], bf, acc[t], 0, 0, 0);
            }
        }

        // prefetch next tile's A-frags (hidden under hh-write + GEMM2)
        const int ntile = tile + 256;
        s16x8 afn[4];
        #pragma unroll
        for (int kb = 0; kb < 4; ++kb) afn[kb] = s16x8{};
        if (ntile < nt) {
            const int arow = ntile * 64 + wave * 16 + m16;
            if (arow < M) {
                #pragma unroll
                for (int kb = 0; kb < 4; ++kb)
                    afn[kb] = *(const s16x8*)(A + (size_t)arow * 128 + kb * 32 + quad * 8);
            }
        }

        // relu + bf16 -> hh (swizzled scatter)
        #pragma unroll
        for (int t = 0; t < 16; ++t) {
            const int col = t * 16 + m16;
            #pragma unroll
            for (int r = 0; r < 4; ++r) {
                const int row = quad * 4 + r;
                float v = acc[t][r] + b1v[t];
                v = v > 0.f ? v : 0.f;
                hh[(hbase + row * 256 + col) ^ ((row & 7) << 3)] = f2bf(v);
            }
        }
        __syncthreads();

        // GEMM2: 16 rows x 128 cols from hh
        f32x4 acc2[8];
        #pragma unroll
        for (int t = 0; t < 8; ++t) acc2[t] = f32x4{0, 0, 0, 0};
        #pragma unroll
        for (int kb = 0; kb < 8; ++kb) {
            s16x8 haf = *(const s16x8*)(hh + ((hbase + m16 * 256 + kb * 32 + quad * 8) ^ ((m16 & 7) << 3)));
            #pragma unroll
            for (int t = 0; t < 8; ++t) {
                s16x8 bf = *(const s16x8*)(w2 + (((((t << 3) | kb) << 6) | lane) * 8));
                acc2[t] = __builtin_amdgcn_mfma_f32_16x16x32_bf16(haf, bf, acc2[t], 0, 0, 0);
            }
        }

        // epilogue
        #pragma unroll
        for (int t = 0; t < 8; ++t) {
            const int col = t * 16 + m16;
            #pragma unroll
            for (int r = 0; r < 4; ++r) {
                const int row = row0 + quad * 4 + r;
                if (row < M) {
                    float v = acc2[t][r] + b2v[t];
                    if (RELU2) v = v > 0.f ? v : 0.f;
                    if (OUTF32) ((float*)C)[(size_t)row * 128 + col] = v;
                    else        ((u16*)C)[(size_t)row * 128 + col] = f2bf(v);
                }
            }
        }
        __syncthreads();   // hh consumed before next tile overwrites it

        #pragma unroll
        for (int kb = 0; kb < 4; ++kb) af[kb] = afn[kb];
    }
}

extern "C" void kernel_launch(void* const* d_in, const int* in_sizes, int n_in,
                              void* d_out, int out_size, void* d_ws, size_t ws_size,
                              hipStream_t stream) {
    const int N = in_sizes[0] / D_FEAT;     // 50000
    const int E = in_sizes[1] / 2;          // 800000

    const float* x    = (const float*)d_in[0];
    const int* eidx   = (const int*)d_in[1];
    const int* eattr  = (const int*)d_in[2];
    const float* ee1_0 = (const float*)d_in[3];
    const float* ee2_0 = (const float*)d_in[4];
    const float* W1_0  = (const float*)d_in[5];
    const float* b1_0  = (const float*)d_in[6];
    const float* W2_0  = (const float*)d_in[7];
    const float* b2_0  = (const float*)d_in[8];
    const float* ee1_1 = (const float*)d_in[9];
    const float* ee2_1 = (const float*)d_in[10];
    const float* W1_1  = (const float*)d_in[11];
    const float* b1_1  = (const float*)d_in[12];
    const float* W2_1  = (const float*)d_in[13];
    const float* b2_1  = (const float*)d_in[14];

    const int nb1  = (E + TILE1 - 1) / TILE1;     // 196 pass-1 blocks
    const int bins = (N + 255) / 256;             // 196 buckets

    // workspace
    char* ws = (char*)d_ws;
    size_t off = 0;
    auto alloc = [&](size_t bytes) { size_t o = off; off = (off + bytes + 255) & ~(size_t)255; return o; };
    size_t o_rowstart = alloc((size_t)(N + 1) * 4);
    size_t o_edges    = alloc((size_t)E * 4);
    size_t o_ghist    = alloc((size_t)bins * nb1 * 4);
    size_t o_base     = alloc((size_t)(bins + 1) * 4);
    size_t o_btot     = alloc((size_t)bins * 4);
    size_t o_counts   = alloc((size_t)N * 20);
    size_t o_emb      = alloc(2 * 18 * 128 * 4);
    size_t o_wt       = alloc(4 * 32768 * 2);
    size_t o_aa       = alloc((size_t)N * D_FEAT * 2);

    int*      row_start = (int*)(ws + o_rowstart);
    unsigned* edges     = (unsigned*)(ws + o_edges);
    int*      ghist     = (int*)(ws + o_ghist);
    int*      bbase     = (int*)(ws + o_base);
    int*      btot      = (int*)(ws + o_btot);
    unsigned* countsw   = (unsigned*)(ws + o_counts);
    float*    emb       = (float*)(ws + o_emb);
    u16*      W1t_0     = (u16*)(ws + o_wt);
    u16*      W2t_0     = W1t_0 + 32768;
    u16*      W1t_1     = W2t_0 + 32768;
    u16*      W2t_1     = W1t_1 + 32768;
    u16*      AA        = (u16*)(ws + o_aa);
    u64*      buf1      = (u64*)(ws + o_aa);      // aliases AA (dead before aggregate)

    // d_out (fp32, 25.6 MB) staging: front = X2 (bf16 L0 output), back = xb (bf16 x)
    u16* X2 = (u16*)d_out;
    u16* xb = (u16*)d_out + (size_t)N * D_FEAT;

    const int nt = (N + 63) / 64;                 // 782 row tiles
    const int aggB = (N + 3) / 4;
    const int n4 = N * D_FEAT / 4;
    const int LDS_MLP = 163840;                   // 160 KB

    static bool attr_done = false;
    if (!attr_done) {
        hipFuncSetAttribute((const void*)mlp_kernel<true, false>,
                            hipFuncAttributeMaxDynamicSharedMemorySize, LDS_MLP);
        hipFuncSetAttribute((const void*)mlp_kernel<false, true>,
                            hipFuncAttributeMaxDynamicSharedMemorySize, LDS_MLP);
        attr_done = true;
    }

    tobf16_kernel<<<(n4 + 255) / 256, 256, 0, stream>>>((const float4*)x, xb, n4);

    // CSR build: 2-pass bucket sort, hierarchical scan, no global atomics
    hist1_kernel<<<nb1, 256, 0, stream>>>(eidx + E, ghist, E, nb1, bins);
    scan1a_kernel<<<bins, 256, 0, stream>>>(ghist, btot, nb1);
    scan1b_kernel<<<1, 256, 0, stream>>>(btot, bbase, row_start, bins);
    scatter1_kernel<<<nb1, 256, 0, stream>>>(eidx, eidx + E, eattr, ghist, bbase, buf1, E, nb1, bins);
    bucket2_kernel<<<bins, 256, 0, stream>>>(buf1, bbase, row_start, edges, countsw, N);

    // prep
    emb_kernel<<<dim3(18, 2), 128, 0, stream>>>(ee1_0, ee2_0, ee1_1, ee2_1, emb);
    transpose_kernel<<<dim3(128, 4), 256, 0, stream>>>(W1_0, W2_0, W1_1, W2_1, W1t_0);

    // layer 0: xb -> AA -> X2
    aggregate_kernel<<<aggB, 256, 0, stream>>>(xb, row_start, edges, emb, countsw, AA, N);
    mlp_kernel<true, false><<<256, 256, LDS_MLP, stream>>>(AA, W1t_0, b1_0, W2t_0, b2_0, X2, N, nt);

    // layer 1: X2 -> AA -> d_out (fp32)
    aggregate_kernel<<<aggB, 256, 0, stream>>>(X2, row_start, edges, emb + 18 * 128, countsw, AA, N);
    mlp_kernel<false, true><<<256, 256, LDS_MLP, stream>>>(AA, W1t_1, b1_1, W2t_1, b2_1, d_out, N, nt);
}

// Round 6
// 264.053 us; speedup vs baseline: 1.4840x; 1.0443x over previous
//
#include <hip/hip_runtime.h>

typedef __attribute__((ext_vector_type(8))) short s16x8;
typedef __attribute__((ext_vector_type(4))) float f32x4;
typedef unsigned short u16;
typedef unsigned char u8;
typedef unsigned long long u64;

#define D_FEAT 128
#define TILE1 4096

__device__ __forceinline__ u16 f2bf(float f) {
    unsigned u = __builtin_bit_cast(unsigned, f);
    u = u + 0x7fffu + ((u >> 16) & 1u);   // RNE
    return (u16)(u >> 16);
}

// ---------------- fused prep: tobf16 | hist1 | emb | transpose (independent) ----------------
__global__ __launch_bounds__(256) void prep_kernel(
        const float4* __restrict__ X4, u16* __restrict__ xb, int n4, int nbA,
        const int* __restrict__ dst, int* __restrict__ ghist, int E, int nb1, int bins,
        const float* __restrict__ ee1_0, const float* __restrict__ ee2_0,
        const float* __restrict__ ee1_1, const float* __restrict__ ee2_1,
        float* __restrict__ emb,
        const float* __restrict__ W1_0, const float* __restrict__ W2_0,
        const float* __restrict__ W1_1, const float* __restrict__ W2_1,
        u16* __restrict__ wout) {
    __shared__ int h[256];
    const int t = threadIdx.x;
    int b = blockIdx.x;

    if (b < nbA) {                         // ---- x fp32 -> bf16
        int i = b * 256 + t;
        if (i < n4) {
            float4 v = X4[i];
            uint2 p;
            p.x = (unsigned)f2bf(v.x) | ((unsigned)f2bf(v.y) << 16);
            p.y = (unsigned)f2bf(v.z) | ((unsigned)f2bf(v.w) << 16);
            *(uint2*)(xb + (size_t)i * 4) = p;
        }
        return;
    }
    b -= nbA;
    if (b < nb1) {                         // ---- per-(bucket, block) histogram
        h[t] = 0;
        __syncthreads();
        const int base = b * TILE1;
        #pragma unroll
        for (int j = 0; j < TILE1 / 256; ++j) {
            int e = base + j * 256 + t;
            if (e < E) atomicAdd(&h[dst[e] >> 8], 1);
        }
        __syncthreads();
        if (t < bins) ghist[t * nb1 + b] = h[t];
        return;
    }
    b -= nb1;
    if (b < 18) {                          // ---- edge-code embedding table (2 layers x 18 x 128)
        int gi = b * 256 + t;              // 0..4607
        int layer = gi / 2304;
        int rem = gi - layer * 2304;
        int code = rem >> 7;
        int d = rem & 127;
        int a0 = code / 3, a1 = code - a0 * 3;
        const float* e1 = layer ? ee1_1 : ee1_0;
        const float* e2 = layer ? ee2_1 : ee2_0;
        emb[layer * 2304 + code * 128 + d] = e1[a0 * 128 + d] + e2[a1 * 128 + d];
        return;
    }
    b -= 18;
    {                                      // ---- weight transpose fp32 -> bf16 (4 mats x 128 blocks)
        int mat = b >> 7;
        const float* s = (mat == 0) ? W1_0 : (mat == 1) ? W2_0 : (mat == 2) ? W1_1 : W2_1;
        int K = (mat & 1) ? 256 : 128;
        int Nc = 384 - K;
        u16* d = wout + mat * 32768;
        int idx = (b & 127) * 256 + t;
        int n = idx / K, k = idx - n * K;
        d[idx] = f2bf(s[k * Nc + n]);
    }
}

// ---------------- scan1a: one block per bucket, scan per-block counts ----------------
__global__ __launch_bounds__(256) void scan1a_kernel(int* __restrict__ ghist,
                                                     int* __restrict__ btot, int nb1) {
    __shared__ int wt[4];
    const int t = threadIdx.x, lane = t & 63, wid = t >> 6;
    const int bin = blockIdx.x;
    const int v = (t < nb1) ? ghist[bin * nb1 + t] : 0;
    int s = v;
    #pragma unroll
    for (int off = 1; off < 64; off <<= 1) {
        int u = __shfl_up(s, off, 64);
        if (lane >= off) s += u;
    }
    if (lane == 63) wt[wid] = s;
    __syncthreads();
    int add = 0;
    #pragma unroll
    for (int w = 0; w < 4; ++w) add += (w < wid) ? wt[w] : 0;
    s += add;                                   // inclusive
    if (t < nb1) ghist[bin * nb1 + t] = s - v;  // exclusive, bucket-relative
    if (t == 255) btot[bin] = s;                // bucket total
}

// ---------------- scatter1: bucket-partitioned scatter; bucket bases from local btot scan ----
__global__ __launch_bounds__(256) void scatter1_kernel(const int* __restrict__ src,
                                                       const int* __restrict__ dst,
                                                       const int* __restrict__ eattr,
                                                       const int* __restrict__ ghist,
                                                       const int* __restrict__ btot,
                                                       u64* __restrict__ buf1,
                                                       int E, int nb1, int bins) {
    __shared__ int lofs[256];
    __shared__ int wt[4];
    const int t = threadIdx.x, lane = t & 63, wid = t >> 6;
    // local exclusive scan of btot -> bucket base, + per-block offset
    const int v = (t < bins) ? btot[t] : 0;
    int s = v;
    #pragma unroll
    for (int off = 1; off < 64; off <<= 1) {
        int u = __shfl_up(s, off, 64);
        if (lane >= off) s += u;
    }
    if (lane == 63) wt[wid] = s;
    __syncthreads();
    int add = 0;
    #pragma unroll
    for (int w = 0; w < 4; ++w) add += (w < wid) ? wt[w] : 0;
    s += add;
    if (t < bins) lofs[t] = (s - v) + ghist[t * nb1 + blockIdx.x];
    __syncthreads();

    const int base = blockIdx.x * TILE1;
    #pragma unroll
    for (int j = 0; j < TILE1 / 256; ++j) {
        int e = base + j * 256 + t;
        if (e < E) {
            int d = dst[e];
            int2 at = ((const int2*)eattr)[e];
            unsigned pay = (unsigned)src[e] | ((unsigned)(at.x * 3 + at.y) << 16);
            int pos = atomicAdd(&lofs[d >> 8], 1);
            buf1[pos] = ((u64)(unsigned)d << 32) | pay;
        }
    }
}

// ---------------- bucket2: counting sort + code histogram, 1024 threads/block ----------------
__global__ __launch_bounds__(1024) void bucket2_kernel(const u64* __restrict__ buf1,
                                                       const int* __restrict__ btot,
                                                       int* __restrict__ row_start,
                                                       unsigned* __restrict__ edges,
                                                       unsigned* __restrict__ countsw,
                                                       int N, int bins) {
    __shared__ int cnt[256];
    __shared__ int cur[256];
    __shared__ int wts[4];
    __shared__ unsigned ccnt[256 * 18];
    __shared__ int sb[2];
    const int t = threadIdx.x, lane = t & 63, wid = t >> 6;
    const int bin = blockIdx.x;

    // phase 0: lo/hi from local btot exclusive scan (first 4 waves)
    int v0 = 0, s0 = 0;
    if (t < 256) {
        v0 = (t < bins) ? btot[t] : 0;
        s0 = v0;
        #pragma unroll
        for (int off = 1; off < 64; off <<= 1) {
            int u = __shfl_up(s0, off, 64);
            if (lane >= off) s0 += u;
        }
        if (lane == 63) wts[wid] = s0;
        cnt[t] = 0;
    }
    for (int i = t; i < 256 * 18; i += 1024) ccnt[i] = 0;
    __syncthreads();
    if (t < 256) {
        int add = 0;
        #pragma unroll
        for (int w = 0; w < 4; ++w) add += (w < wid) ? wts[w] : 0;
        s0 += add;
        if (t == bin) { sb[0] = s0 - v0; sb[1] = s0; }   // lo, hi
    }
    __syncthreads();
    const int lo = sb[0], hi = sb[1];

    // phase 1: node histogram
    for (int i = lo + t; i < hi; i += 1024)
        atomicAdd(&cnt[(int)(buf1[i] >> 32) & 255], 1);
    __syncthreads();

    // phase 2: scan node counts (first 4 waves)
    int v1 = 0, s1 = 0;
    if (t < 256) {
        v1 = cnt[t];
        s1 = v1;
        #pragma unroll
        for (int off = 1; off < 64; off <<= 1) {
            int u = __shfl_up(s1, off, 64);
            if (lane >= off) s1 += u;
        }
        if (lane == 63) wts[wid] = s1;
    }
    __syncthreads();
    if (t < 256) {
        int add = 0;
        #pragma unroll
        for (int w = 0; w < 4; ++w) add += (w < wid) ? wts[w] : 0;
        s1 += add;
        const int g = bin * 256 + t;
        if (g < N) row_start[g + 1] = lo + s1;
        cur[t] = s1 - v1;
        if (bin == 0 && t == 0) row_start[0] = 0;
    }
    __syncthreads();

    // phase 3: scatter + per-node code histogram
    for (int i = lo + t; i < hi; i += 1024) {
        u64 rec = buf1[i];
        const int local = (int)(rec >> 32) & 255;
        int loc = atomicAdd(&cur[local], 1);
        edges[lo + loc] = (unsigned)rec;
        atomicAdd(&ccnt[local * 18 + ((unsigned)rec >> 16)], 1);
    }
    __syncthreads();

    // phase 4: pack counts u8 x18 -> 5 u32 per node
    if (t < 256) {
        const int g = bin * 256 + t;
        if (g < N) {
            unsigned w[5] = {0, 0, 0, 0, 0};
            #pragma unroll
            for (int c = 0; c < 18; ++c)
                w[c >> 2] |= ccnt[t * 18 + c] << (8 * (c & 3));
            #pragma unroll
            for (int k = 0; k < 5; ++k)
                countsw[(size_t)g * 5 + k] = w[k];
        }
    }
}

// ---------------- aggregation: one wave per node ----------------
// Edge loop: readlane-broadcast gathers, ~4 VALU/edge, no per-edge LDS.
// Edge-embedding term folded into per-node epilogue via code counts.
__global__ __launch_bounds__(256) void aggregate_kernel(const u16* __restrict__ X,
                                                        const int* __restrict__ row_start,
                                                        const unsigned* __restrict__ edges,
                                                        const float* __restrict__ emb,
                                                        const unsigned* __restrict__ countsw,
                                                        u16* __restrict__ A, int N) {
    __shared__ float semb[18 * 128];
    for (int i = threadIdx.x; i < 18 * 128; i += 256) semb[i] = emb[i];
    __syncthreads();
    const int node = blockIdx.x * 4 + (threadIdx.x >> 6);
    const int lane = threadIdx.x & 63;
    if (node >= N) return;

    unsigned cw[5];
    #pragma unroll
    for (int k = 0; k < 5; ++k) cw[k] = countsw[(size_t)node * 5 + k];

    int s = __builtin_amdgcn_readfirstlane(row_start[node]);
    const int e = __builtin_amdgcn_readfirstlane(row_start[node + 1]);
    const float2* sem2 = (const float2*)semb;
    float a0 = 0.f, a1 = 0.f;

    while (s < e) {
        const int take = (e - s < 64) ? (e - s) : 64;             // wave-uniform
        unsigned pl = edges[s + (lane < take ? lane : 0)];        // 1 coalesced load
        #pragma unroll
        for (int c = 0; c < 4; ++c) {
            const int cb = c * 16;
            if (cb < take) {                                      // uniform branch
                unsigned ps[16];
                unsigned xv[16];
                #pragma unroll
                for (int j = 0; j < 16; ++j)
                    ps[j] = __builtin_amdgcn_readlane(pl, cb + j);  // SGPR broadcast
                #pragma unroll
                for (int j = 0; j < 16; ++j)
                    xv[j] = *(const unsigned*)(X + (ps[j] & 0xFFFFu) * D_FEAT + lane * 2);
                #pragma unroll
                for (int j = 0; j < 16; ++j) {
                    const float m = (cb + j < take) ? 1.f : 0.f;  // uniform mask
                    a0 += m * __builtin_bit_cast(float, xv[j] << 16);
                    a1 += m * __builtin_bit_cast(float, xv[j] & 0xFFFF0000u);
                }
            }
        }
        s += take;
    }

    // epilogue: + sum_c count_c * emb[c][dim]
    #pragma unroll
    for (int w = 0; w < 5; ++w) {
        #pragma unroll
        for (int b = 0; b < 4; ++b) {
            const int code = w * 4 + b;
            if (code < 18) {
                const float cf = (float)((cw[w] >> (8 * b)) & 255u);
                float2 ev = sem2[code * 64 + lane];
                a0 += cf * ev.x;
                a1 += cf * ev.y;
            }
        }
    }

    unsigned outp = (unsigned)f2bf(a0) | ((unsigned)f2bf(a1) << 16);
    *(unsigned*)(A + node * D_FEAT + lane * 2) = outp;
}

// ---------------- persistent-weight fused MLP ----------------
template <bool RELU2, bool OUTF32>
__global__ __launch_bounds__(256, 1) void mlp_kernel(const u16* __restrict__ A,
                                                     const u16* __restrict__ B1t,
                                                     const float* __restrict__ bias1,
                                                     const u16* __restrict__ B2t,
                                                     const float* __restrict__ bias2,
                                                     void* __restrict__ C, int M, int nt) {
    extern __shared__ __align__(16) u16 lds[];
    u16* w1 = lds;              // 32768 u16
    u16* w2 = lds + 32768;      // 32768 u16
    u16* hh = lds + 65536;      // 16384 u16, XOR-swizzled
    const int tid = threadIdx.x;
    const int wave = tid >> 6;
    const int lane = tid & 63;
    const int m16 = lane & 15;
    const int quad = lane >> 4;

    {
        const uint4* src1 = (const uint4*)B1t;
        const uint4* src2 = (const uint4*)B2t;
        #pragma unroll
        for (int i = 0; i < 16; ++i) {
            int s = i * 256 + tid;
            uint4 v = src1[s];
            int c = (((s >> 8) * 4 + ((s >> 2) & 3)) << 6) | ((s & 3) << 4) | ((s >> 4) & 15);
            *(uint4*)(w1 + c * 8) = v;
        }
        #pragma unroll
        for (int i = 0; i < 16; ++i) {
            int s = i * 256 + tid;
            uint4 v = src2[s];
            int c = (((s >> 9) * 8 + ((s >> 2) & 7)) << 6) | ((s & 3) << 4) | ((s >> 5) & 15);
            *(uint4*)(w2 + c * 8) = v;
        }
    }
    float b1v[16];
    #pragma unroll
    for (int t = 0; t < 16; ++t) b1v[t] = bias1[t * 16 + m16];
    float b2v[8];
    #pragma unroll
    for (int t = 0; t < 8; ++t) b2v[t] = bias2[t * 16 + m16];

    const int hbase = wave * 4096;

    int tile = blockIdx.x;
    s16x8 af[4];
    #pragma unroll
    for (int kb = 0; kb < 4; ++kb) af[kb] = s16x8{};
    if (tile < nt) {
        const int arow = tile * 64 + wave * 16 + m16;
        if (arow < M) {
            #pragma unroll
            for (int kb = 0; kb < 4; ++kb)
                af[kb] = *(const s16x8*)(A + (size_t)arow * 128 + kb * 32 + quad * 8);
        }
    }

    __syncthreads();

    for (; tile < nt; tile += 256) {
        const int row0 = tile * 64 + wave * 16;

        f32x4 acc[16];
        #pragma unroll
        for (int t = 0; t < 16; ++t) acc[t] = f32x4{0, 0, 0, 0};
        #pragma unroll
        for (int kb = 0; kb < 4; ++kb) {
            #pragma unroll
            for (int t = 0; t < 16; ++t) {
                s16x8 bf = *(const s16x8*)(w1 + (((((t << 2) | kb) << 6) | lane) * 8));
                acc[t] = __builtin_amdgcn_mfma_f32_16x16x32_bf16(af[kb], bf, acc[t], 0, 0, 0);
            }
        }

        const int ntile = tile + 256;
        s16x8 afn[4];
        #pragma unroll
        for (int kb = 0; kb < 4; ++kb) afn[kb] = s16x8{};
        if (ntile < nt) {
            const int arow = ntile * 64 + wave * 16 + m16;
            if (arow < M) {
                #pragma unroll
                for (int kb = 0; kb < 4; ++kb)
                    afn[kb] = *(const s16x8*)(A + (size_t)arow * 128 + kb * 32 + quad * 8);
            }
        }

        #pragma unroll
        for (int t = 0; t < 16; ++t) {
            const int col = t * 16 + m16;
            #pragma unroll
            for (int r = 0; r < 4; ++r) {
                const int row = quad * 4 + r;
                float v = acc[t][r] + b1v[t];
                v = v > 0.f ? v : 0.f;
                hh[(hbase + row * 256 + col) ^ ((row & 7) << 3)] = f2bf(v);
            }
        }
        __syncthreads();

        f32x4 acc2[8];
        #pragma unroll
        for (int t = 0; t < 8; ++t) acc2[t] = f32x4{0, 0, 0, 0};
        #pragma unroll
        for (int kb = 0; kb < 8; ++kb) {
            s16x8 haf = *(const s16x8*)(hh + ((hbase + m16 * 256 + kb * 32 + quad * 8) ^ ((m16 & 7) << 3)));
            #pragma unroll
            for (int t = 0; t < 8; ++t) {
                s16x8 bf = *(const s16x8*)(w2 + (((((t << 3) | kb) << 6) | lane) * 8));
                acc2[t] = __builtin_amdgcn_mfma_f32_16x16x32_bf16(haf, bf, acc2[t], 0, 0, 0);
            }
        }

        #pragma unroll
        for (int t = 0; t < 8; ++t) {
            const int col = t * 16 + m16;
            #pragma unroll
            for (int r = 0; r < 4; ++r) {
                const int row = row0 + quad * 4 + r;
                if (row < M) {
                    float v = acc2[t][r] + b2v[t];
                    if (RELU2) v = v > 0.f ? v : 0.f;
                    if (OUTF32) ((float*)C)[(size_t)row * 128 + col] = v;
                    else        ((u16*)C)[(size_t)row * 128 + col] = f2bf(v);
                }
            }
        }
        __syncthreads();

        #pragma unroll
        for (int kb = 0; kb < 4; ++kb) af[kb] = afn[kb];
    }
}

extern "C" void kernel_launch(void* const* d_in, const int* in_sizes, int n_in,
                              void* d_out, int out_size, void* d_ws, size_t ws_size,
                              hipStream_t stream) {
    const int N = in_sizes[0] / D_FEAT;     // 50000
    const int E = in_sizes[1] / 2;          // 800000

    const float* x    = (const float*)d_in[0];
    const int* eidx   = (const int*)d_in[1];
    const int* eattr  = (const int*)d_in[2];
    const float* ee1_0 = (const float*)d_in[3];
    const float* ee2_0 = (const float*)d_in[4];
    const float* W1_0  = (const float*)d_in[5];
    const float* b1_0  = (const float*)d_in[6];
    const float* W2_0  = (const float*)d_in[7];
    const float* b2_0  = (const float*)d_in[8];
    const float* ee1_1 = (const float*)d_in[9];
    const float* ee2_1 = (const float*)d_in[10];
    const float* W1_1  = (const float*)d_in[11];
    const float* b1_1  = (const float*)d_in[12];
    const float* W2_1  = (const float*)d_in[13];
    const float* b2_1  = (const float*)d_in[14];

    const int nb1  = (E + TILE1 - 1) / TILE1;     // 196
    const int bins = (N + 255) / 256;             // 196

    char* ws = (char*)d_ws;
    size_t off = 0;
    auto alloc = [&](size_t bytes) { size_t o = off; off = (off + bytes + 255) & ~(size_t)255; return o; };
    size_t o_rowstart = alloc((size_t)(N + 1) * 4);
    size_t o_edges    = alloc((size_t)E * 4);
    size_t o_ghist    = alloc((size_t)bins * nb1 * 4);
    size_t o_btot     = alloc((size_t)bins * 4);
    size_t o_counts   = alloc((size_t)N * 20);
    size_t o_emb      = alloc(2 * 18 * 128 * 4);
    size_t o_wt       = alloc(4 * 32768 * 2);
    size_t o_aa       = alloc((size_t)N * D_FEAT * 2);

    int*      row_start = (int*)(ws + o_rowstart);
    unsigned* edges     = (unsigned*)(ws + o_edges);
    int*      ghist     = (int*)(ws + o_ghist);
    int*      btot      = (int*)(ws + o_btot);
    unsigned* countsw   = (unsigned*)(ws + o_counts);
    float*    emb       = (float*)(ws + o_emb);
    u16*      W1t_0     = (u16*)(ws + o_wt);
    u16*      W2t_0     = W1t_0 + 32768;
    u16*      W1t_1     = W2t_0 + 32768;
    u16*      W2t_1     = W1t_1 + 32768;
    u16*      AA        = (u16*)(ws + o_aa);
    u64*      buf1      = (u64*)(ws + o_aa);      // aliases AA (dead before aggregate)

    u16* X2 = (u16*)d_out;
    u16* xb = (u16*)d_out + (size_t)N * D_FEAT;

    const int nt = (N + 63) / 64;                 // 782
    const int aggB = (N + 3) / 4;
    const int n4 = N * D_FEAT / 4;
    const int nbA = (n4 + 255) / 256;             // 6250
    const int LDS_MLP = 163840;

    static bool attr_done = false;
    if (!attr_done) {
        hipFuncSetAttribute((const void*)mlp_kernel<true, false>,
                            hipFuncAttributeMaxDynamicSharedMemorySize, LDS_MLP);
        hipFuncSetAttribute((const void*)mlp_kernel<false, true>,
                            hipFuncAttributeMaxDynamicSharedMemorySize, LDS_MLP);
        attr_done = true;
    }

    // 1) fused prep: tobf16 | hist1 | emb | transpose
    prep_kernel<<<nbA + nb1 + 18 + 512, 256, 0, stream>>>(
        (const float4*)x, xb, n4, nbA,
        eidx + E, ghist, E, nb1, bins,
        ee1_0, ee2_0, ee1_1, ee2_1, emb,
        W1_0, W2_0, W1_1, W2_1, W1t_0);

    // 2-4) CSR build
    scan1a_kernel<<<bins, 256, 0, stream>>>(ghist, btot, nb1);
    scatter1_kernel<<<nb1, 256, 0, stream>>>(eidx, eidx + E, eattr, ghist, btot, buf1, E, nb1, bins);
    bucket2_kernel<<<bins, 1024, 0, stream>>>(buf1, btot, row_start, edges, countsw, N, bins);

    // 5-6) layer 0
    aggregate_kernel<<<aggB, 256, 0, stream>>>(xb, row_start, edges, emb, countsw, AA, N);
    mlp_kernel<true, false><<<256, 256, LDS_MLP, stream>>>(AA, W1t_0, b1_0, W2t_0, b2_0, X2, N, nt);

    // 7-8) layer 1
    aggregate_kernel<<<aggB, 256, 0, stream>>>(X2, row_start, edges, emb + 18 * 128, countsw, AA, N);
    mlp_kernel<false, true><<<256, 256, LDS_MLP, stream>>>(AA, W1t_1, b1_1, W2t_1, b2_1, d_out, N, nt);
}